// Round 8
// baseline (1004.381 us; speedup 1.0000x reference)
//
#include <hip/hip_runtime.h>
#include <hip/hip_bf16.h>

// 4-layer SRU. L=4, B=32, T=512, D=512, V=1000. f32 inputs, f32 output.
// R7: (a) GEMM staging via global_load_lds width=16 (m97 pattern), unpadded
//     LDS tiles; (b) scan rewritten producer/consumer: waves 1-3 stream the
//     4 operand planes into a double-buffered LDS ring via global_load_lds
//     size=4, wave 0 runs the serial c-chain off LDS (lgkmcnt-decoupled).

#define LAYERS 4
#define BB 32
#define TT 512
#define DD 512
#define N3 1536
#define MROWS (TT * BB)
#define WPL ((size_t)DD * N3)   // 786432 elems per layer ([n][k] = 1536*512)
#define SB 32                   // scan ring-buffer steps per phase

typedef unsigned short u16;
typedef short bshort8 __attribute__((ext_vector_type(8)));
typedef float f32x4 __attribute__((ext_vector_type(4)));

__device__ __forceinline__ float b2f(u16 u) {
  union { unsigned int i; float f; } x;
  x.i = ((unsigned int)u) << 16;
  return x.f;
}
__device__ __forceinline__ u16 f2b(float f) {  // RNE
  union { float f; unsigned int i; } x;
  x.f = f;
  unsigned int r = (x.i + 0x7FFFu + ((x.i >> 16) & 1u)) >> 16;
  return (u16)r;
}

__device__ __forceinline__ void async_ld16(const void* g, void* l) {
  __builtin_amdgcn_global_load_lds(
      (const __attribute__((address_space(1))) void*)g,
      (__attribute__((address_space(3))) void*)l, 16, 0, 0);
}
__device__ __forceinline__ void async_ld4(const void* g, void* l) {
  __builtin_amdgcn_global_load_lds(
      (const __attribute__((address_space(1))) void*)g,
      (__attribute__((address_space(3))) void*)l, 4, 0, 0);
}

// ---- dtype detection (flags[0]: floats f32, [1]: mask bytes, [2]: ids int64)
__global__ void detect_kernel(const u16* __restrict__ emb_u,
                              const int* __restrict__ mask_i,
                              const int* __restrict__ ids_i,
                              int* __restrict__ flags) {
  __shared__ int cnt[3];
  __shared__ int zc;
  int tid = threadIdx.x;
  if (tid < 3) cnt[tid] = 0;
  if (tid == 0) zc = 0;
  __syncthreads();
  int bad = 0, zero_even = 0;
  for (int i = tid; i < 8192; i += 256) {
    u16 u = emb_u[i];
    unsigned e = (u >> 7) & 0xFF;
    if (e >= 0x8F) bad++;
    if ((i & 1) == 0 && u == 0) zero_even++;
  }
  if (bad) atomicAdd(&cnt[0], bad);
  if (zero_even) atomicAdd(&zc, zero_even);
  if (tid < 64) {
    unsigned vv = (unsigned)mask_i[tid];
    if (vv > 1u) atomicAdd(&cnt[1], 1);
  }
  if (tid < 256) {
    if (ids_i[2 * tid + 1] == 0) atomicAdd(&cnt[2], 1);
  }
  __syncthreads();
  if (tid == 0) {
    flags[0] = (cnt[0] > 64 || zc > 3000) ? 1 : 0;
    flags[1] = (cnt[1] > 0) ? 1 : 0;
    flags[2] = (cnt[2] >= 192) ? 1 : 0;
  }
}

// ---- W split+transpose: Wst[l][s][n][k] bf16, s=0 hi, s=1 lo -----------
__global__ __launch_bounds__(256)
void wprep_kernel(const void* __restrict__ W, u16* __restrict__ Wst,
                  const int* __restrict__ flags) {
  __shared__ float tileW[32][33];
  int l = blockIdx.z;
  int k0 = blockIdx.x * 32;
  int n0 = blockIdx.y * 32;
  int tx = threadIdx.x & 31;
  int ty = threadIdx.x >> 5;  // 0..7
  int ff = flags[0];
  const float* Wf = (const float*)W + (size_t)l * WPL;
  const u16* Wb = (const u16*)W + (size_t)l * WPL;
  for (int kk = ty; kk < 32; kk += 8) {
    size_t off = (size_t)(k0 + kk) * N3 + n0 + tx;
    tileW[kk][tx] = ff ? Wf[off] : b2f(Wb[off]);
  }
  __syncthreads();
  u16* hiP = Wst + (size_t)l * 2 * WPL;
  u16* loP = hiP + WPL;
  for (int nn = ty; nn < 32; nn += 8) {
    float x = tileW[tx][nn];
    u16 hi = f2b(x);
    u16 lo = f2b(x - b2f(hi));
    size_t o = (size_t)(n0 + nn) * DD + k0 + tx;
    hiP[o] = hi;
    loP[o] = lo;
  }
}

// ---- embedding: X f32 (B,T,D) = d_out; Xh/Xl bf16 (T,B,D) --------------
__global__ void embed_kernel(const int* __restrict__ ids,
                             const void* __restrict__ emb,
                             float* __restrict__ X,
                             u16* __restrict__ Xh, u16* __restrict__ Xl,
                             const int* __restrict__ flags) {
  int i = blockIdx.x * 256 + threadIdx.x;  // (t,b,d) linear
  int d = i & (DD - 1);
  int tb = i >> 9;
  int b = tb & (BB - 1);
  int t = tb >> 5;
  int ii = b * TT + t;
  int id = flags[2] ? ids[2 * ii] : ids[ii];
  float val = flags[0] ? ((const float*)emb)[id * DD + d]
                       : b2f(((const u16*)emb)[id * DD + d]);
  X[((size_t)b * TT + t) * DD + d] = val;
  u16 hi = f2b(val);
  Xh[i] = hi;
  Xl[i] = f2b(val - b2f(hi));
}

// ---- MFMA GEMM with async LDS staging ----------------------------------
// U[chunkM,1536] = split-f32 X * W_l. virtual K=1536 (3 passes over K=512).
// 128x128 tile, 4 waves (2x2 of 64x64), 16x16x32 bf16 MFMA.
// Staging: waves 0,1 stage A rows 0-63/64-127; waves 2,3 stage B.
// Each wave: 4x global_load_lds(16B) = 4KB; LDS rows unpadded 64B
// (dest = uniform base + lane*16: lane l -> row l/4, 16B-seg l%4).
__global__ __launch_bounds__(256)
void gemm_kernel(const u16* __restrict__ Xh, const u16* __restrict__ Xl,
                 const u16* __restrict__ Ws,  // layer base [2][1536][512]
                 float* __restrict__ U, int row_base) {
  __shared__ u16 At[128][32];
  __shared__ u16 Bt[128][32];
  const int tid = threadIdx.x;
  const int row0 = blockIdx.x * 128;
  const int col0 = blockIdx.y * 128;
  const int lane = tid & 63, wave = tid >> 6;
  const int wm = (wave >> 1) * 64, wn = (wave & 1) * 64;
  const int m16 = lane & 15, quad = lane >> 4;
  const int isA = (wave < 2);
  const int rbase = (wave & 1) * 64;   // tile-row base this wave stages
  const int srow = lane >> 2;          // 0..15 row within 16-row chunk
  const int sseg = lane & 3;           // 16B (8 u16) segment within row

  f32x4 acc[4][4];
#pragma unroll
  for (int mi = 0; mi < 4; ++mi)
#pragma unroll
    for (int ni = 0; ni < 4; ++ni)
#pragma unroll
      for (int r = 0; r < 4; ++r) acc[mi][ni][r] = 0.f;

  for (int kv = 0; kv < 1536; kv += 32) {
    int p = kv >> 9;
    int k0 = kv & 511;
    const u16* Asrc = (p == 2) ? Xl : Xh;
    const u16* Bsrc = Ws + ((p == 1) ? WPL : 0);

    __syncthreads();  // previous iteration's ds_reads complete
    if (isA) {
      const u16* src = Asrc + (size_t)(row_base + row0 + rbase + srow) * DD +
                       k0 + sseg * 8;
#pragma unroll
      for (int i = 0; i < 4; ++i)
        async_ld16(src + (size_t)i * 16 * DD, &At[rbase + i * 16][0]);
    } else {
      const u16* src = Bsrc + (size_t)(col0 + rbase + srow) * DD + k0 + sseg * 8;
#pragma unroll
      for (int i = 0; i < 4; ++i)
        async_ld16(src + (size_t)i * 16 * DD, &Bt[rbase + i * 16][0]);
    }
    __syncthreads();  // async loads landed (vmcnt drained at barrier)

    bshort8 af[4], bfr[4];
#pragma unroll
    for (int i = 0; i < 4; ++i) {
      af[i] = *(const bshort8*)&At[wm + i * 16 + m16][quad * 8];
      bfr[i] = *(const bshort8*)&Bt[wn + i * 16 + m16][quad * 8];
    }
#pragma unroll
    for (int mi = 0; mi < 4; ++mi)
#pragma unroll
      for (int ni = 0; ni < 4; ++ni)
        acc[mi][ni] = __builtin_amdgcn_mfma_f32_16x16x32_bf16(
            af[mi], bfr[ni], acc[mi][ni], 0, 0, 0);
  }

#pragma unroll
  for (int mi = 0; mi < 4; ++mi) {
    int r0 = row0 + wm + mi * 16 + quad * 4;
#pragma unroll
    for (int ni = 0; ni < 4; ++ni) {
      int cix = col0 + wn + ni * 16 + m16;
#pragma unroll
      for (int reg = 0; reg < 4; ++reg)
        U[(size_t)(r0 + reg) * N3 + cix] = acc[mi][ni][reg];
    }
  }
}

// ---- SRU scan: producer/consumer wave specialization -------------------
// Block = 256 threads: wave 0 consumes (serial c-chain per lane, 64 chains
// of one b), waves 1-3 produce the 4 operand streams into LDS double buffer
// via global_load_lds(4B). One __syncthreads per SB steps.
template <int EMIT>
__global__ __launch_bounds__(256, 1)
void scan_kernel(const float* __restrict__ U, float* __restrict__ X,
                 u16* __restrict__ Xh, u16* __restrict__ Xl,
                 const void* __restrict__ mask_p, const void* __restrict__ vbase,
                 const void* __restrict__ bbase, int layer,
                 const int* __restrict__ flags, float* __restrict__ carry,
                 int t0, int nt) {
  __shared__ float buf[2][4][SB][64];  // phase, stream(xt,fp,rp,xi), step, lane
  __shared__ int msk[TT];
  const int tid = threadIdx.x;
  const int wave = tid >> 6, lane = tid & 63;
  const int idx0 = blockIdx.x * 64;  // chain base in [0, B*D)
  const int b = idx0 >> 9;           // one b per block
  const int d0 = idx0 & 511;
  const int ff = flags[0], fm = flags[1];

  const int* mi_ = (const int*)mask_p + b * TT;
  const unsigned char* mb_ = (const unsigned char*)mask_p + b * TT;
  for (int i = tid; i < nt; i += 256) msk[i] = fm ? (int)mb_[t0 + i] : mi_[t0 + i];

  float vf = 0.f, vr = 0.f, bf_ = 0.f, br_ = 0.f, c = 0.f;
  if (wave == 0) {
    int d = d0 + lane;
    size_t voff = (size_t)layer * 2 * DD;
    if (ff) {
      const float* vp = (const float*)vbase + voff;
      const float* bp2 = (const float*)bbase + voff;
      vf = vp[d]; vr = vp[DD + d]; bf_ = bp2[d]; br_ = bp2[DD + d];
    } else {
      const u16* vp = (const u16*)vbase + voff;
      const u16* bp2 = (const u16*)bbase + voff;
      vf = b2f(vp[d]); vr = b2f(vp[DD + d]); bf_ = b2f(bp2[d]); br_ = b2f(bp2[DD + d]);
    }
    c = (t0 == 0) ? 0.f : carry[idx0 + lane];
  }

  const int nbuf = nt / SB;

  // producer routine: fill buffer phase ph with chunk-local steps [k*SB, k*SB+SB)
  auto produce = [&](int k, int ph) {
    int tl = k * SB;                         // chunk-local step base
    if (wave == 1) {
      const float* ub = U + ((size_t)tl * BB + b) * N3 + d0 + lane;  // xt plane
      const float* xb = X + ((size_t)b * TT + t0 + tl) * DD + d0 + lane;
#pragma unroll
      for (int s = 0; s < SB; ++s)
        async_ld4(ub + (size_t)s * BB * N3, &buf[ph][0][s][0]);
#pragma unroll
      for (int s = 0; s < SB; ++s)
        async_ld4(xb + (size_t)s * DD, &buf[ph][3][s][0]);
    } else if (wave == 2) {
      const float* ub = U + ((size_t)tl * BB + b) * N3 + 512 + d0 + lane;  // fp
#pragma unroll
      for (int s = 0; s < SB; ++s)
        async_ld4(ub + (size_t)s * BB * N3, &buf[ph][1][s][0]);
    } else if (wave == 3) {
      const float* ub = U + ((size_t)tl * BB + b) * N3 + 1024 + d0 + lane;  // rp
#pragma unroll
      for (int s = 0; s < SB; ++s)
        async_ld4(ub + (size_t)s * BB * N3, &buf[ph][2][s][0]);
    }
  };

  if (wave > 0) produce(0, 0);

  float* Xp = X + (size_t)b * TT * DD + d0 + lane;

  for (int k = 0; k < nbuf; ++k) {
    __syncthreads();  // buffer k ready (producers drained vmcnt at barrier)
    int ph = k & 1;
    if (wave > 0) {
      if (k + 1 < nbuf) produce(k + 1, ph ^ 1);
    } else {
#pragma unroll 4
      for (int s = 0; s < SB; ++s) {
        int tl = k * SB + s;
        float xt = buf[ph][0][s][lane];
        float fp = buf[ph][1][s][lane];
        float rp = buf[ph][2][s][lane];
        float xin = buf[ph][3][s][lane];
        int m = msk[tl];
        float zf = fp + vf * c + bf_;
        float zr = rp + vr * c + br_;
        float f = 1.f / (1.f + __expf(-zf));
        float r = 1.f / (1.f + __expf(-zr));
        float cn = f * c + (1.f - f) * xt;
        float e2 = __expf(2.f * cn);
        float th = (e2 - 1.f) / (e2 + 1.f);
        float h = r * th + (1.f - r) * xin;
        bool pad = (m == 0);
        c = pad ? c : cn;
        float hout = pad ? 0.f : h;
        int tg = t0 + tl;
        Xp[(size_t)tg * DD] = hout;
        if (EMIT) {
          u16 hi = f2b(hout);
          size_t o = ((size_t)tg * BB + b) * DD + d0 + lane;
          Xh[o] = hi;
          Xl[o] = f2b(hout - b2f(hi));
        }
      }
    }
  }
  if (wave == 0) carry[idx0 + lane] = c;
}

__global__ void sentinel_kernel(float* out) { out[threadIdx.x] = 12345.f; }

extern "C" void kernel_launch(void* const* d_in, const int* in_sizes, int n_in,
                              void* d_out, int out_size, void* d_ws, size_t ws_size,
                              hipStream_t stream) {
  const int* ids = (const int*)d_in[0];
  const void* mask = d_in[1];
  const void* emb = d_in[2];
  const void* W = d_in[3];
  const void* v = d_in[4];
  const void* bp = d_in[5];

  char* ws = (char*)d_ws;
  int* flags = (int*)ws;                      // 4 KiB
  float* carry = (float*)(ws + 4096);         // 64 KiB
  const size_t offXh = 69632;
  const size_t offXl = offXh + (size_t)MROWS * DD * 2;       // +16 MiB
  const size_t offWs = offXl + (size_t)MROWS * DD * 2;       // +16 MiB
  const size_t offU = offWs + (size_t)LAYERS * 2 * WPL * 2;  // +12 MiB
  const size_t perT = (size_t)BB * N3 * 4;    // 196608 B / timestep

  const int cand[5] = {512, 256, 128, 64, 32};  // multiples of SB
  int chunkT = 0;
  for (int i = 0; i < 5; ++i) {
    if (ws_size >= offU + (size_t)cand[i] * perT) { chunkT = cand[i]; break; }
  }
  if (!chunkT) {
    sentinel_kernel<<<1, 256, 0, stream>>>((float*)d_out);
    return;
  }

  u16* Xh = (u16*)(ws + offXh);
  u16* Xl = (u16*)(ws + offXl);
  u16* Wst = (u16*)(ws + offWs);
  float* U = (float*)(ws + offU);
  float* X = (float*)d_out;  // (B,T,D) f32

  detect_kernel<<<1, 256, 0, stream>>>((const u16*)emb, (const int*)mask,
                                       (const int*)ids, flags);
  wprep_kernel<<<dim3(16, 48, 4), 256, 0, stream>>>(W, Wst, flags);
  embed_kernel<<<MROWS * DD / 256, 256, 0, stream>>>(ids, emb, X, Xh, Xl, flags);

  int nch = TT / chunkT;
  for (int l = 0; l < LAYERS; ++l) {
    const u16* Wsl = Wst + (size_t)l * 2 * WPL;
    for (int ch = 0; ch < nch; ++ch) {
      int t0 = ch * chunkT;
      dim3 g(chunkT * BB / 128, N3 / 128);
      gemm_kernel<<<g, 256, 0, stream>>>(Xh, Xl, Wsl, U, t0 * BB);
      if (l < LAYERS - 1)
        scan_kernel<1><<<BB * DD / 64, 256, 0, stream>>>(U, X, Xh, Xl, mask, v, bp,
                                                         l, flags, carry, t0, chunkT);
      else
        scan_kernel<0><<<BB * DD / 64, 256, 0, stream>>>(U, X, Xh, Xl, mask, v, bp,
                                                         l, flags, carry, t0, chunkT);
    }
  }
}

// Round 9
// 639.717 us; speedup vs baseline: 1.5700x; 1.5700x over previous
//
#include <hip/hip_runtime.h>
#include <hip/hip_bf16.h>

// 4-layer SRU. L=4, B=32, T=512, D=512, V=1000. f32 inputs, f32 output.
// R8: single-pass fp16 GEMM (K=512, BK=64) with XOR-swizzled async LDS
// staging (conflict-free ds_read_b128 + contiguous global_load_lds dest),
// biases folded into U planes in the epilogue; scan: 1 consumer + 4
// balanced producer waves, f16 X16 emit.

#define LAYERS 4
#define BB 32
#define TT 512
#define DD 512
#define N3 1536
#define MROWS (TT * BB)
#define WPL ((size_t)DD * N3)   // 786432 elems per layer ([n][k] = 1536*512)
#define SB 32                   // scan ring-buffer steps per phase

typedef unsigned short u16;
typedef _Float16 half8 __attribute__((ext_vector_type(8)));
typedef float f32x4 __attribute__((ext_vector_type(4)));

__device__ __forceinline__ float b2f(u16 u) {
  union { unsigned int i; float f; } x;
  x.i = ((unsigned int)u) << 16;
  return x.f;
}
__device__ __forceinline__ u16 f2h(float f) {
  _Float16 h = (_Float16)f;
  return *(u16*)&h;
}

__device__ __forceinline__ void async_ld16(const void* g, void* l) {
  __builtin_amdgcn_global_load_lds(
      (const __attribute__((address_space(1))) void*)g,
      (__attribute__((address_space(3))) void*)l, 16, 0, 0);
}
__device__ __forceinline__ void async_ld4(const void* g, void* l) {
  __builtin_amdgcn_global_load_lds(
      (const __attribute__((address_space(1))) void*)g,
      (__attribute__((address_space(3))) void*)l, 4, 0, 0);
}

// ---- dtype detection (flags[0]: floats f32, [1]: mask bytes, [2]: ids int64)
__global__ void detect_kernel(const u16* __restrict__ emb_u,
                              const int* __restrict__ mask_i,
                              const int* __restrict__ ids_i,
                              int* __restrict__ flags) {
  __shared__ int cnt[3];
  __shared__ int zc;
  int tid = threadIdx.x;
  if (tid < 3) cnt[tid] = 0;
  if (tid == 0) zc = 0;
  __syncthreads();
  int bad = 0, zero_even = 0;
  for (int i = tid; i < 8192; i += 256) {
    u16 u = emb_u[i];
    unsigned e = (u >> 7) & 0xFF;
    if (e >= 0x8F) bad++;
    if ((i & 1) == 0 && u == 0) zero_even++;
  }
  if (bad) atomicAdd(&cnt[0], bad);
  if (zero_even) atomicAdd(&zc, zero_even);
  if (tid < 64) {
    unsigned vv = (unsigned)mask_i[tid];
    if (vv > 1u) atomicAdd(&cnt[1], 1);
  }
  if (tid < 256) {
    if (ids_i[2 * tid + 1] == 0) atomicAdd(&cnt[2], 1);
  }
  __syncthreads();
  if (tid == 0) {
    flags[0] = (cnt[0] > 64 || zc > 3000) ? 1 : 0;
    flags[1] = (cnt[1] > 0) ? 1 : 0;
    flags[2] = (cnt[2] >= 192) ? 1 : 0;
  }
}

// ---- W -> f16 transpose: W16[l][n][k] ----------------------------------
__global__ __launch_bounds__(256)
void wprep_kernel(const void* __restrict__ W, u16* __restrict__ W16,
                  const int* __restrict__ flags) {
  __shared__ float tileW[32][33];
  int l = blockIdx.z;
  int k0 = blockIdx.x * 32;
  int n0 = blockIdx.y * 32;
  int tx = threadIdx.x & 31;
  int ty = threadIdx.x >> 5;  // 0..7
  int ff = flags[0];
  const float* Wf = (const float*)W + (size_t)l * WPL;
  const u16* Wb = (const u16*)W + (size_t)l * WPL;
  for (int kk = ty; kk < 32; kk += 8) {
    size_t off = (size_t)(k0 + kk) * N3 + n0 + tx;
    tileW[kk][tx] = ff ? Wf[off] : b2f(Wb[off]);
  }
  __syncthreads();
  u16* outP = W16 + (size_t)l * WPL;
  for (int nn = ty; nn < 32; nn += 8) {
    float x = tileW[tx][nn];
    outP[(size_t)(n0 + nn) * DD + k0 + tx] = f2h(x);
  }
}

// ---- embedding: X f32 (B,T,D) = d_out; X16 f16 (T,B,D) -----------------
__global__ void embed_kernel(const int* __restrict__ ids,
                             const void* __restrict__ emb,
                             float* __restrict__ X,
                             u16* __restrict__ X16,
                             const int* __restrict__ flags) {
  int i = blockIdx.x * 256 + threadIdx.x;  // (t,b,d) linear
  int d = i & (DD - 1);
  int tb = i >> 9;
  int b = tb & (BB - 1);
  int t = tb >> 5;
  int ii = b * TT + t;
  int id = flags[2] ? ids[2 * ii] : ids[ii];
  float val = flags[0] ? ((const float*)emb)[id * DD + d]
                       : b2f(((const u16*)emb)[id * DD + d]);
  X[((size_t)b * TT + t) * DD + d] = val;
  X16[i] = f2h(val);
}

// ---- MFMA fp16 GEMM: U[chunkM,1536] = X16 * W16_l, biases folded -------
// 128x128 tile, K=512, BK=64, 4 waves (2x2 of 64x64), 16x16x32 f16 MFMA.
// Staging: waves 0,1 stage A row-halves; waves 2,3 stage B. XOR swizzle:
// LDS slot (row, segPhys) holds global k-segment segPhys^(row&7).
__global__ __launch_bounds__(256)
void gemm_kernel(const u16* __restrict__ X16, const u16* __restrict__ W16l,
                 const void* __restrict__ bvec, int layer,
                 const int* __restrict__ flags,
                 float* __restrict__ U, int row_base) {
  __shared__ u16 At[128][64];
  __shared__ u16 Bt[128][64];
  const int tid = threadIdx.x;
  const int row0 = blockIdx.x * 128;
  const int col0 = blockIdx.y * 128;
  const int lane = tid & 63, wave = tid >> 6;
  const int wm = (wave >> 1) * 64, wn = (wave & 1) * 64;
  const int m16 = lane & 15, quad = lane >> 4;
  const int isA = (wave < 2);
  const int rbase = (wave & 1) * 64;   // 64-row half this wave stages
  const int srow = lane >> 3;          // 0..7 row within 8-row chunk
  const int sseg = (lane & 7) ^ (srow & 7);  // swizzled k-segment (8 f16)

  f32x4 acc[4][4];
#pragma unroll
  for (int mi = 0; mi < 4; ++mi)
#pragma unroll
    for (int ni = 0; ni < 4; ++ni)
#pragma unroll
      for (int r = 0; r < 4; ++r) acc[mi][ni][r] = 0.f;

  const u16* srcBase = isA ? X16 : W16l;
  const int gbase = isA ? (row_base + row0 + rbase) : (col0 + rbase);

  for (int kv = 0; kv < 512; kv += 64) {
    __syncthreads();  // previous iteration's ds_reads complete
    {
      const u16* src = srcBase + (size_t)(gbase + srow) * DD + kv + sseg * 8;
      u16(*dst)[64] = isA ? At : Bt;
#pragma unroll
      for (int i = 0; i < 8; ++i)
        async_ld16(src + (size_t)i * 8 * DD, &dst[rbase + i * 8][0]);
    }
    __syncthreads();  // async loads landed (vmcnt drained at barrier)

    half8 af[2][4], bfr[2][4];
#pragma unroll
    for (int kk = 0; kk < 2; ++kk)
#pragma unroll
      for (int i = 0; i < 4; ++i) {
        int ra = wm + i * 16 + m16;
        af[kk][i] = *(const half8*)&At[ra][((kk * 4 + quad) ^ (ra & 7)) * 8];
        int rb = wn + i * 16 + m16;
        bfr[kk][i] = *(const half8*)&Bt[rb][((kk * 4 + quad) ^ (rb & 7)) * 8];
      }
#pragma unroll
    for (int kk = 0; kk < 2; ++kk)
#pragma unroll
      for (int mi = 0; mi < 4; ++mi)
#pragma unroll
        for (int ni = 0; ni < 4; ++ni)
          acc[mi][ni] = __builtin_amdgcn_mfma_f32_16x16x32_f16(
              af[kk][mi], bfr[kk][ni], acc[mi][ni], 0, 0, 0);
  }

  // epilogue: plane p = cix>>9 gets bias (p=1: bf, p=2: br) folded in
  const int ff = flags[0];
#pragma unroll
  for (int ni = 0; ni < 4; ++ni) {
    int cix = col0 + wn + ni * 16 + m16;
    int p = cix >> 9;
    int dd = cix & 511;
    float bias = 0.f;
    if (p > 0) {
      size_t bo = (size_t)layer * 2 * DD + (size_t)(p - 1) * DD + dd;
      bias = ff ? ((const float*)bvec)[bo] : b2f(((const u16*)bvec)[bo]);
    }
#pragma unroll
    for (int mi = 0; mi < 4; ++mi) {
      int r0 = row0 + wm + mi * 16 + quad * 4;
#pragma unroll
      for (int reg = 0; reg < 4; ++reg)
        U[(size_t)(r0 + reg) * N3 + cix] = acc[mi][ni][reg] + bias;
    }
  }
}

// ---- SRU scan: 1 consumer wave + 4 producer waves (one stream each) ----
template <int EMIT>
__global__ __launch_bounds__(320, 1)
void scan_kernel(const float* __restrict__ U, float* __restrict__ X,
                 u16* __restrict__ X16,
                 const void* __restrict__ mask_p, const void* __restrict__ vbase,
                 int layer, const int* __restrict__ flags,
                 float* __restrict__ carry, int t0, int nt) {
  __shared__ float buf[2][4][SB][64];  // phase, stream(xt,fp,rp,xi), step, lane
  __shared__ int msk[TT];
  const int tid = threadIdx.x;
  const int wave = tid >> 6, lane = tid & 63;
  const int idx0 = blockIdx.x * 64;  // chain base in [0, B*D)
  const int b = idx0 >> 9;           // one b per block
  const int d0 = idx0 & 511;
  const int ff = flags[0], fm = flags[1];

  const int* mi_ = (const int*)mask_p + b * TT;
  const unsigned char* mb_ = (const unsigned char*)mask_p + b * TT;
  for (int i = tid; i < nt; i += 320) msk[i] = fm ? (int)mb_[t0 + i] : mi_[t0 + i];

  float vf = 0.f, vr = 0.f, c = 0.f;
  if (wave == 0) {
    int d = d0 + lane;
    size_t voff = (size_t)layer * 2 * DD;
    if (ff) {
      const float* vp = (const float*)vbase + voff;
      vf = vp[d]; vr = vp[DD + d];
    } else {
      const u16* vp = (const u16*)vbase + voff;
      vf = b2f(vp[d]); vr = b2f(vp[DD + d]);
    }
    c = (t0 == 0) ? 0.f : carry[idx0 + lane];
  }

  const int nbuf = nt / SB;

  // producer: wave w (1..4) fills stream w-1 of buffer phase ph
  auto produce = [&](int k, int ph) {
    int tl = k * SB;
    if (wave == 4) {  // xin from X f32
      const float* xb = X + ((size_t)b * TT + t0 + tl) * DD + d0 + lane;
#pragma unroll
      for (int s = 0; s < SB; ++s)
        async_ld4(xb + (size_t)s * DD, &buf[ph][3][s][0]);
    } else {  // U planes 0,1,2
      const float* ub = U + ((size_t)tl * BB + b) * N3 + (wave - 1) * 512 +
                        d0 + lane;
#pragma unroll
      for (int s = 0; s < SB; ++s)
        async_ld4(ub + (size_t)s * BB * N3, &buf[ph][wave - 1][s][0]);
    }
  };

  if (wave > 0) produce(0, 0);

  float* Xp = X + (size_t)b * TT * DD + d0 + lane;

  for (int k = 0; k < nbuf; ++k) {
    __syncthreads();  // buffer k ready
    int ph = k & 1;
    if (wave > 0) {
      if (k + 1 < nbuf) produce(k + 1, ph ^ 1);
    } else {
#pragma unroll 4
      for (int s = 0; s < SB; ++s) {
        int tl = k * SB + s;
        float xt = buf[ph][0][s][lane];
        float fp = buf[ph][1][s][lane];
        float rp = buf[ph][2][s][lane];
        float xin = buf[ph][3][s][lane];
        int m = msk[tl];
        float zf = fp + vf * c;            // biases pre-folded in GEMM
        float zr = rp + vr * c;
        float f = 1.f / (1.f + __expf(-zf));
        float r = 1.f / (1.f + __expf(-zr));
        float cn = f * c + (1.f - f) * xt;
        float e2 = __expf(2.f * cn);
        float th = (e2 - 1.f) / (e2 + 1.f);
        float h = r * th + (1.f - r) * xin;
        bool pad = (m == 0);
        c = pad ? c : cn;
        float hout = pad ? 0.f : h;
        int tg = t0 + tl;
        Xp[(size_t)tg * DD] = hout;
        if (EMIT)
          X16[((size_t)tg * BB + b) * DD + d0 + lane] = f2h(hout);
      }
    }
  }
  if (wave == 0) carry[idx0 + lane] = c;
}

__global__ void sentinel_kernel(float* out) { out[threadIdx.x] = 12345.f; }

extern "C" void kernel_launch(void* const* d_in, const int* in_sizes, int n_in,
                              void* d_out, int out_size, void* d_ws, size_t ws_size,
                              hipStream_t stream) {
  const int* ids = (const int*)d_in[0];
  const void* mask = d_in[1];
  const void* emb = d_in[2];
  const void* W = d_in[3];
  const void* v = d_in[4];
  const void* bp = d_in[5];

  char* ws = (char*)d_ws;
  int* flags = (int*)ws;                      // 4 KiB
  float* carry = (float*)(ws + 4096);         // 64 KiB
  const size_t offX16 = 69632;
  const size_t offW16 = offX16 + (size_t)MROWS * DD * 2;   // +16 MiB
  const size_t offU = offW16 + (size_t)LAYERS * WPL * 2;   // +6 MiB
  const size_t perT = (size_t)BB * N3 * 4;    // 196608 B / timestep

  const int cand[5] = {512, 256, 128, 64, 32};  // multiples of SB
  int chunkT = 0;
  for (int i = 0; i < 5; ++i) {
    if (ws_size >= offU + (size_t)cand[i] * perT) { chunkT = cand[i]; break; }
  }
  if (!chunkT) {
    sentinel_kernel<<<1, 256, 0, stream>>>((float*)d_out);
    return;
  }

  u16* X16 = (u16*)(ws + offX16);
  u16* W16 = (u16*)(ws + offW16);
  float* U = (float*)(ws + offU);
  float* X = (float*)d_out;  // (B,T,D) f32

  detect_kernel<<<1, 256, 0, stream>>>((const u16*)emb, (const int*)mask,
                                       (const int*)ids, flags);
  wprep_kernel<<<dim3(16, 48, 4), 256, 0, stream>>>(W, W16, flags);
  embed_kernel<<<MROWS * DD / 256, 256, 0, stream>>>(ids, emb, X, X16, flags);

  int nch = TT / chunkT;
  for (int l = 0; l < LAYERS; ++l) {
    const u16* W16l = W16 + (size_t)l * WPL;
    for (int ch = 0; ch < nch; ++ch) {
      int t0 = ch * chunkT;
      dim3 g(chunkT * BB / 128, N3 / 128);
      gemm_kernel<<<g, 256, 0, stream>>>(X16, W16l, bp, l, flags, U, t0 * BB);
      if (l < LAYERS - 1)
        scan_kernel<1><<<BB * DD / 64, 320, 0, stream>>>(U, X, X16, mask, v, l,
                                                         flags, carry, t0, chunkT);
      else
        scan_kernel<0><<<BB * DD / 64, 320, 0, stream>>>(U, X, X16, mask, v, l,
                                                         flags, carry, t0, chunkT);
    }
  }
}

// Round 10
// 591.126 us; speedup vs baseline: 1.6991x; 1.0822x over previous
//
#include <hip/hip_runtime.h>
#include <hip/hip_bf16.h>

// 4-layer SRU. L=4, B=32, T=512, D=512, V=1000. f32 inputs, f32 output.
// R9: scan split across waves: wave0 = serial c-chain (minimal work),
// wave1 = r/tanh/h/store path at one-phase lag (no carried deps), waves
// 2-3 = operand producers via global_load_lds. GEMM/embed/wprep from R8.

#define LAYERS 4
#define BB 32
#define TT 512
#define DD 512
#define N3 1536
#define MROWS (TT * BB)
#define WPL ((size_t)DD * N3)
#define SB 32                   // steps per phase

typedef unsigned short u16;
typedef _Float16 half8 __attribute__((ext_vector_type(8)));
typedef float f32x4 __attribute__((ext_vector_type(4)));

__device__ __forceinline__ float b2f(u16 u) {
  union { unsigned int i; float f; } x;
  x.i = ((unsigned int)u) << 16;
  return x.f;
}
__device__ __forceinline__ u16 f2h(float f) {
  _Float16 h = (_Float16)f;
  return *(u16*)&h;
}

__device__ __forceinline__ void async_ld16(const void* g, void* l) {
  __builtin_amdgcn_global_load_lds(
      (const __attribute__((address_space(1))) void*)g,
      (__attribute__((address_space(3))) void*)l, 16, 0, 0);
}
__device__ __forceinline__ void async_ld4(const void* g, void* l) {
  __builtin_amdgcn_global_load_lds(
      (const __attribute__((address_space(1))) void*)g,
      (__attribute__((address_space(3))) void*)l, 4, 0, 0);
}

// ---- dtype detection (flags[0]: floats f32, [1]: mask bytes, [2]: ids int64)
__global__ void detect_kernel(const u16* __restrict__ emb_u,
                              const int* __restrict__ mask_i,
                              const int* __restrict__ ids_i,
                              int* __restrict__ flags) {
  __shared__ int cnt[3];
  __shared__ int zc;
  int tid = threadIdx.x;
  if (tid < 3) cnt[tid] = 0;
  if (tid == 0) zc = 0;
  __syncthreads();
  int bad = 0, zero_even = 0;
  for (int i = tid; i < 8192; i += 256) {
    u16 u = emb_u[i];
    unsigned e = (u >> 7) & 0xFF;
    if (e >= 0x8F) bad++;
    if ((i & 1) == 0 && u == 0) zero_even++;
  }
  if (bad) atomicAdd(&cnt[0], bad);
  if (zero_even) atomicAdd(&zc, zero_even);
  if (tid < 64) {
    unsigned vv = (unsigned)mask_i[tid];
    if (vv > 1u) atomicAdd(&cnt[1], 1);
  }
  if (tid < 256) {
    if (ids_i[2 * tid + 1] == 0) atomicAdd(&cnt[2], 1);
  }
  __syncthreads();
  if (tid == 0) {
    flags[0] = (cnt[0] > 64 || zc > 3000) ? 1 : 0;
    flags[1] = (cnt[1] > 0) ? 1 : 0;
    flags[2] = (cnt[2] >= 192) ? 1 : 0;
  }
}

// ---- W -> f16 transpose: W16[l][n][k] ----------------------------------
__global__ __launch_bounds__(256)
void wprep_kernel(const void* __restrict__ W, u16* __restrict__ W16,
                  const int* __restrict__ flags) {
  __shared__ float tileW[32][33];
  int l = blockIdx.z;
  int k0 = blockIdx.x * 32;
  int n0 = blockIdx.y * 32;
  int tx = threadIdx.x & 31;
  int ty = threadIdx.x >> 5;
  int ff = flags[0];
  const float* Wf = (const float*)W + (size_t)l * WPL;
  const u16* Wb = (const u16*)W + (size_t)l * WPL;
  for (int kk = ty; kk < 32; kk += 8) {
    size_t off = (size_t)(k0 + kk) * N3 + n0 + tx;
    tileW[kk][tx] = ff ? Wf[off] : b2f(Wb[off]);
  }
  __syncthreads();
  u16* outP = W16 + (size_t)l * WPL;
  for (int nn = ty; nn < 32; nn += 8) {
    float x = tileW[tx][nn];
    outP[(size_t)(n0 + nn) * DD + k0 + tx] = f2h(x);
  }
}

// ---- embedding: X f32 (B,T,D) = d_out; X16 f16 (T,B,D) -----------------
__global__ void embed_kernel(const int* __restrict__ ids,
                             const void* __restrict__ emb,
                             float* __restrict__ X,
                             u16* __restrict__ X16,
                             const int* __restrict__ flags) {
  int i = blockIdx.x * 256 + threadIdx.x;
  int d = i & (DD - 1);
  int tb = i >> 9;
  int b = tb & (BB - 1);
  int t = tb >> 5;
  int ii = b * TT + t;
  int id = flags[2] ? ids[2 * ii] : ids[ii];
  float val = flags[0] ? ((const float*)emb)[id * DD + d]
                       : b2f(((const u16*)emb)[id * DD + d]);
  X[((size_t)b * TT + t) * DD + d] = val;
  X16[i] = f2h(val);
}

// ---- MFMA fp16 GEMM (R8): K=512, BK=64, XOR-swizzled async staging -----
__global__ __launch_bounds__(256)
void gemm_kernel(const u16* __restrict__ X16, const u16* __restrict__ W16l,
                 const void* __restrict__ bvec, int layer,
                 const int* __restrict__ flags,
                 float* __restrict__ U, int row_base) {
  __shared__ u16 At[128][64];
  __shared__ u16 Bt[128][64];
  const int tid = threadIdx.x;
  const int row0 = blockIdx.x * 128;
  const int col0 = blockIdx.y * 128;
  const int lane = tid & 63, wave = tid >> 6;
  const int wm = (wave >> 1) * 64, wn = (wave & 1) * 64;
  const int m16 = lane & 15, quad = lane >> 4;
  const int isA = (wave < 2);
  const int rbase = (wave & 1) * 64;
  const int srow = lane >> 3;
  const int sseg = (lane & 7) ^ (srow & 7);

  f32x4 acc[4][4];
#pragma unroll
  for (int mi = 0; mi < 4; ++mi)
#pragma unroll
    for (int ni = 0; ni < 4; ++ni)
#pragma unroll
      for (int r = 0; r < 4; ++r) acc[mi][ni][r] = 0.f;

  const u16* srcBase = isA ? X16 : W16l;
  const int gbase = isA ? (row_base + row0 + rbase) : (col0 + rbase);

  for (int kv = 0; kv < 512; kv += 64) {
    __syncthreads();
    {
      const u16* src = srcBase + (size_t)(gbase + srow) * DD + kv + sseg * 8;
      u16(*dst)[64] = isA ? At : Bt;
#pragma unroll
      for (int i = 0; i < 8; ++i)
        async_ld16(src + (size_t)i * 8 * DD, &dst[rbase + i * 8][0]);
    }
    __syncthreads();

    half8 af[2][4], bfr[2][4];
#pragma unroll
    for (int kk = 0; kk < 2; ++kk)
#pragma unroll
      for (int i = 0; i < 4; ++i) {
        int ra = wm + i * 16 + m16;
        af[kk][i] = *(const half8*)&At[ra][((kk * 4 + quad) ^ (ra & 7)) * 8];
        int rb = wn + i * 16 + m16;
        bfr[kk][i] = *(const half8*)&Bt[rb][((kk * 4 + quad) ^ (rb & 7)) * 8];
      }
#pragma unroll
    for (int kk = 0; kk < 2; ++kk)
#pragma unroll
      for (int mi = 0; mi < 4; ++mi)
#pragma unroll
        for (int ni = 0; ni < 4; ++ni)
          acc[mi][ni] = __builtin_amdgcn_mfma_f32_16x16x32_f16(
              af[kk][mi], bfr[kk][ni], acc[mi][ni], 0, 0, 0);
  }

  const int ff = flags[0];
#pragma unroll
  for (int ni = 0; ni < 4; ++ni) {
    int cix = col0 + wn + ni * 16 + m16;
    int p = cix >> 9;
    int dd = cix & 511;
    float bias = 0.f;
    if (p > 0) {
      size_t bo = (size_t)layer * 2 * DD + (size_t)(p - 1) * DD + dd;
      bias = ff ? ((const float*)bvec)[bo] : b2f(((const u16*)bvec)[bo]);
    }
#pragma unroll
    for (int mi = 0; mi < 4; ++mi) {
      int r0 = row0 + wm + mi * 16 + quad * 4;
#pragma unroll
      for (int reg = 0; reg < 4; ++reg)
        U[(size_t)(r0 + reg) * N3 + cix] = acc[mi][ni][reg] + bias;
    }
  }
}

// ---- SRU scan: split-recurrence, 4 waves -------------------------------
// wave0: c-chain (f path), publishes (c_prev, cn) ring.  wave1: h path at
// one-phase lag + stores.  wave2: xt/fp producer.  wave3: rp/xi producer.
// Buffers: A(xt,fp) double, B(rp,xi) triple (read 2 phases after write),
// ring double. One barrier per SB steps.
template <int EMIT>
__global__ __launch_bounds__(256, 1)
void scan_kernel(const float* __restrict__ U, float* __restrict__ X,
                 u16* __restrict__ X16,
                 const void* __restrict__ mask_p, const void* __restrict__ vbase,
                 int layer, const int* __restrict__ flags,
                 float* __restrict__ carry, int t0, int nt) {
  __shared__ float bufA[2][2][SB][64];   // [parity][xt|fp][step][lane]
  __shared__ float bufB[3][2][SB][64];   // [k%3][rp|xi][step][lane]
  __shared__ float ring[2][2][SB][64];   // [parity][cprev|cn][step][lane]
  __shared__ int msk[TT];
  const int tid = threadIdx.x;
  const int wave = tid >> 6, lane = tid & 63;
  const int idx0 = blockIdx.x * 64;  // chain base in [0, B*D)
  const int b = idx0 >> 9;           // one b per block
  const int d0 = idx0 & 511;
  const int ff = flags[0], fm = flags[1];

  const int* mi_ = (const int*)mask_p + b * TT;
  const unsigned char* mb_ = (const unsigned char*)mask_p + b * TT;
  for (int i = tid; i < nt; i += 256) msk[i] = fm ? (int)mb_[t0 + i] : mi_[t0 + i];

  float vf = 0.f, vr = 0.f, c = 0.f;
  {
    int d = d0 + lane;
    size_t voff = (size_t)layer * 2 * DD;
    if (wave == 0) {
      vf = ff ? ((const float*)vbase)[voff + d] : b2f(((const u16*)vbase)[voff + d]);
      c = (t0 == 0) ? 0.f : carry[idx0 + lane];
    } else if (wave == 1) {
      vr = ff ? ((const float*)vbase)[voff + DD + d]
              : b2f(((const u16*)vbase)[voff + DD + d]);
    }
  }

  const int nbuf = nt / SB;

  auto produceA = [&](int k) {  // wave2
    int ph = k & 1, tl = k * SB;
    const float* u0 = U + ((size_t)tl * BB + b) * N3 + d0 + lane;
#pragma unroll
    for (int s = 0; s < SB; ++s)
      async_ld4(u0 + (size_t)s * BB * N3, &bufA[ph][0][s][0]);
#pragma unroll
    for (int s = 0; s < SB; ++s)
      async_ld4(u0 + 512 + (size_t)s * BB * N3, &bufA[ph][1][s][0]);
  };
  auto produceB = [&](int k) {  // wave3
    int ph = k % 3, tl = k * SB;
    const float* u2 = U + ((size_t)tl * BB + b) * N3 + 1024 + d0 + lane;
    const float* xb = X + ((size_t)b * TT + t0 + tl) * DD + d0 + lane;
#pragma unroll
    for (int s = 0; s < SB; ++s)
      async_ld4(u2 + (size_t)s * BB * N3, &bufB[ph][0][s][0]);
#pragma unroll
    for (int s = 0; s < SB; ++s)
      async_ld4(xb + (size_t)s * DD, &bufB[ph][1][s][0]);
  };

  float* Xp = X + (size_t)b * TT * DD + d0 + lane;

  auto hphase = [&](int j) {  // wave1: h for phase j
    int phc = j & 1, phb = j % 3;
#pragma unroll 4
    for (int s = 0; s < SB; ++s) {
      float cprev = ring[phc][0][s][lane];
      float cn = ring[phc][1][s][lane];
      float rp = bufB[phb][0][s][lane];
      float xin = bufB[phb][1][s][lane];
      int m = msk[j * SB + s];
      float zr = rp + vr * cprev;
      float r = 1.f / (1.f + __expf(-zr));
      float e2 = __expf(2.f * cn);
      float th = (e2 - 1.f) / (e2 + 1.f);
      float h = r * (th - xin) + xin;
      float hout = (m == 0) ? 0.f : h;
      int tg = t0 + j * SB + s;
      Xp[(size_t)tg * DD] = hout;
      if (EMIT)
        X16[((size_t)tg * BB + b) * DD + d0 + lane] = f2h(hout);
    }
  };

  if (wave == 2) produceA(0);
  if (wave == 3) produceB(0);

  for (int k = 0; k < nbuf; ++k) {
    __syncthreads();  // phase-k operands ready; ring[k-1] ready
    if (wave == 2) {
      if (k + 1 < nbuf) produceA(k + 1);
    } else if (wave == 3) {
      if (k + 1 < nbuf) produceB(k + 1);
    } else if (wave == 0) {
      int ph = k & 1;
#pragma unroll 8
      for (int s = 0; s < SB; ++s) {
        float xt = bufA[ph][0][s][lane];
        float fp = bufA[ph][1][s][lane];
        float zf = fp + vf * c;  // bias pre-folded in GEMM
        float f = 1.f / (1.f + __expf(-zf));
        float cn = f * (c - xt) + xt;
        ring[ph][0][s][lane] = c;
        ring[ph][1][s][lane] = cn;
        c = (msk[k * SB + s] == 0) ? c : cn;
      }
    } else {  // wave 1
      if (k > 0) hphase(k - 1);
    }
  }
  __syncthreads();  // last ring phase visible
  if (wave == 1) hphase(nbuf - 1);
  if (wave == 0) carry[idx0 + lane] = c;
}

__global__ void sentinel_kernel(float* out) { out[threadIdx.x] = 12345.f; }

extern "C" void kernel_launch(void* const* d_in, const int* in_sizes, int n_in,
                              void* d_out, int out_size, void* d_ws, size_t ws_size,
                              hipStream_t stream) {
  const int* ids = (const int*)d_in[0];
  const void* mask = d_in[1];
  const void* emb = d_in[2];
  const void* W = d_in[3];
  const void* v = d_in[4];
  const void* bp = d_in[5];

  char* ws = (char*)d_ws;
  int* flags = (int*)ws;                      // 4 KiB
  float* carry = (float*)(ws + 4096);         // 64 KiB
  const size_t offX16 = 69632;
  const size_t offW16 = offX16 + (size_t)MROWS * DD * 2;   // +16 MiB
  const size_t offU = offW16 + (size_t)LAYERS * WPL * 2;   // +6 MiB
  const size_t perT = (size_t)BB * N3 * 4;    // 196608 B / timestep

  const int cand[4] = {512, 256, 128, 64};  // multiples of 2*SB
  int chunkT = 0;
  for (int i = 0; i < 4; ++i) {
    if (ws_size >= offU + (size_t)cand[i] * perT) { chunkT = cand[i]; break; }
  }
  if (!chunkT) {
    sentinel_kernel<<<1, 256, 0, stream>>>((float*)d_out);
    return;
  }

  u16* X16 = (u16*)(ws + offX16);
  u16* W16 = (u16*)(ws + offW16);
  float* U = (float*)(ws + offU);
  float* X = (float*)d_out;  // (B,T,D) f32

  detect_kernel<<<1, 256, 0, stream>>>((const u16*)emb, (const int*)mask,
                                       (const int*)ids, flags);
  wprep_kernel<<<dim3(16, 48, 4), 256, 0, stream>>>(W, W16, flags);
  embed_kernel<<<MROWS * DD / 256, 256, 0, stream>>>(ids, emb, X, X16, flags);

  int nch = TT / chunkT;
  for (int l = 0; l < LAYERS; ++l) {
    const u16* W16l = W16 + (size_t)l * WPL;
    for (int ch = 0; ch < nch; ++ch) {
      int t0 = ch * chunkT;
      dim3 g(chunkT * BB / 128, N3 / 128);
      gemm_kernel<<<g, 256, 0, stream>>>(X16, W16l, bp, l, flags, U, t0 * BB);
      if (l < LAYERS - 1)
        scan_kernel<1><<<BB * DD / 64, 256, 0, stream>>>(U, X, X16, mask, v, l,
                                                         flags, carry, t0, chunkT);
      else
        scan_kernel<0><<<BB * DD / 64, 256, 0, stream>>>(U, X, X16, mask, v, l,
                                                         flags, carry, t0, chunkT);
    }
  }
}

// Round 11
// 477.949 us; speedup vs baseline: 2.1014x; 1.2368x over previous
//
#include <hip/hip_runtime.h>
#include <hip/hip_bf16.h>

// 4-layer SRU. L=4, B=32, T=512, D=512, V=1000. f32 inputs, f32 output.
// R10: R9 structure; transcendental chain rebuilt: exact f32 divisions ->
// v_rcp_f32 (3 sites), exp inputs pre-scaled by -log2e in the GEMM epilogue
// so the serial c-chain is fma -> v_exp -> add -> rcp -> fma (~48 cyc).

#define LAYERS 4
#define BB 32
#define TT 512
#define DD 512
#define N3 1536
#define MROWS (TT * BB)
#define WPL ((size_t)DD * N3)
#define SB 32                   // steps per phase
#define LOG2E 1.4426950408889634f
#define TWOLOG2E 2.8853900817779268f

typedef unsigned short u16;
typedef _Float16 half8 __attribute__((ext_vector_type(8)));
typedef float f32x4 __attribute__((ext_vector_type(4)));

__device__ __forceinline__ float b2f(u16 u) {
  union { unsigned int i; float f; } x;
  x.i = ((unsigned int)u) << 16;
  return x.f;
}
__device__ __forceinline__ u16 f2h(float f) {
  _Float16 h = (_Float16)f;
  return *(u16*)&h;
}
__device__ __forceinline__ float rcpf(float x) { return __builtin_amdgcn_rcpf(x); }
__device__ __forceinline__ float exp2f_(float x) { return __builtin_amdgcn_exp2f(x); }

__device__ __forceinline__ void async_ld16(const void* g, void* l) {
  __builtin_amdgcn_global_load_lds(
      (const __attribute__((address_space(1))) void*)g,
      (__attribute__((address_space(3))) void*)l, 16, 0, 0);
}
__device__ __forceinline__ void async_ld4(const void* g, void* l) {
  __builtin_amdgcn_global_load_lds(
      (const __attribute__((address_space(1))) void*)g,
      (__attribute__((address_space(3))) void*)l, 4, 0, 0);
}

// ---- dtype detection (flags[0]: floats f32, [1]: mask bytes, [2]: ids int64)
__global__ void detect_kernel(const u16* __restrict__ emb_u,
                              const int* __restrict__ mask_i,
                              const int* __restrict__ ids_i,
                              int* __restrict__ flags) {
  __shared__ int cnt[3];
  __shared__ int zc;
  int tid = threadIdx.x;
  if (tid < 3) cnt[tid] = 0;
  if (tid == 0) zc = 0;
  __syncthreads();
  int bad = 0, zero_even = 0;
  for (int i = tid; i < 8192; i += 256) {
    u16 u = emb_u[i];
    unsigned e = (u >> 7) & 0xFF;
    if (e >= 0x8F) bad++;
    if ((i & 1) == 0 && u == 0) zero_even++;
  }
  if (bad) atomicAdd(&cnt[0], bad);
  if (zero_even) atomicAdd(&zc, zero_even);
  if (tid < 64) {
    unsigned vv = (unsigned)mask_i[tid];
    if (vv > 1u) atomicAdd(&cnt[1], 1);
  }
  if (tid < 256) {
    if (ids_i[2 * tid + 1] == 0) atomicAdd(&cnt[2], 1);
  }
  __syncthreads();
  if (tid == 0) {
    flags[0] = (cnt[0] > 64 || zc > 3000) ? 1 : 0;
    flags[1] = (cnt[1] > 0) ? 1 : 0;
    flags[2] = (cnt[2] >= 192) ? 1 : 0;
  }
}

// ---- W -> f16 transpose: W16[l][n][k] ----------------------------------
__global__ __launch_bounds__(256)
void wprep_kernel(const void* __restrict__ W, u16* __restrict__ W16,
                  const int* __restrict__ flags) {
  __shared__ float tileW[32][33];
  int l = blockIdx.z;
  int k0 = blockIdx.x * 32;
  int n0 = blockIdx.y * 32;
  int tx = threadIdx.x & 31;
  int ty = threadIdx.x >> 5;
  int ff = flags[0];
  const float* Wf = (const float*)W + (size_t)l * WPL;
  const u16* Wb = (const u16*)W + (size_t)l * WPL;
  for (int kk = ty; kk < 32; kk += 8) {
    size_t off = (size_t)(k0 + kk) * N3 + n0 + tx;
    tileW[kk][tx] = ff ? Wf[off] : b2f(Wb[off]);
  }
  __syncthreads();
  u16* outP = W16 + (size_t)l * WPL;
  for (int nn = ty; nn < 32; nn += 8) {
    float x = tileW[tx][nn];
    outP[(size_t)(n0 + nn) * DD + k0 + tx] = f2h(x);
  }
}

// ---- embedding: X f32 (B,T,D) = d_out; X16 f16 (T,B,D) -----------------
__global__ void embed_kernel(const int* __restrict__ ids,
                             const void* __restrict__ emb,
                             float* __restrict__ X,
                             u16* __restrict__ X16,
                             const int* __restrict__ flags) {
  int i = blockIdx.x * 256 + threadIdx.x;
  int d = i & (DD - 1);
  int tb = i >> 9;
  int b = tb & (BB - 1);
  int t = tb >> 5;
  int ii = b * TT + t;
  int id = flags[2] ? ids[2 * ii] : ids[ii];
  float val = flags[0] ? ((const float*)emb)[id * DD + d]
                       : b2f(((const u16*)emb)[id * DD + d]);
  X[((size_t)b * TT + t) * DD + d] = val;
  X16[i] = f2h(val);
}

// ---- MFMA fp16 GEMM (R8): K=512, BK=64, XOR-swizzled async staging -----
// Epilogue: plane0 = acc (xt); planes 1,2 = -(acc+bias)*log2e (exp-ready).
__global__ __launch_bounds__(256)
void gemm_kernel(const u16* __restrict__ X16, const u16* __restrict__ W16l,
                 const void* __restrict__ bvec, int layer,
                 const int* __restrict__ flags,
                 float* __restrict__ U, int row_base) {
  __shared__ u16 At[128][64];
  __shared__ u16 Bt[128][64];
  const int tid = threadIdx.x;
  const int row0 = blockIdx.x * 128;
  const int col0 = blockIdx.y * 128;
  const int lane = tid & 63, wave = tid >> 6;
  const int wm = (wave >> 1) * 64, wn = (wave & 1) * 64;
  const int m16 = lane & 15, quad = lane >> 4;
  const int isA = (wave < 2);
  const int rbase = (wave & 1) * 64;
  const int srow = lane >> 3;
  const int sseg = (lane & 7) ^ (srow & 7);

  f32x4 acc[4][4];
#pragma unroll
  for (int mi = 0; mi < 4; ++mi)
#pragma unroll
    for (int ni = 0; ni < 4; ++ni)
#pragma unroll
      for (int r = 0; r < 4; ++r) acc[mi][ni][r] = 0.f;

  const u16* srcBase = isA ? X16 : W16l;
  const int gbase = isA ? (row_base + row0 + rbase) : (col0 + rbase);

  for (int kv = 0; kv < 512; kv += 64) {
    __syncthreads();
    {
      const u16* src = srcBase + (size_t)(gbase + srow) * DD + kv + sseg * 8;
      u16(*dst)[64] = isA ? At : Bt;
#pragma unroll
      for (int i = 0; i < 8; ++i)
        async_ld16(src + (size_t)i * 8 * DD, &dst[rbase + i * 8][0]);
    }
    __syncthreads();

    half8 af[2][4], bfr[2][4];
#pragma unroll
    for (int kk = 0; kk < 2; ++kk)
#pragma unroll
      for (int i = 0; i < 4; ++i) {
        int ra = wm + i * 16 + m16;
        af[kk][i] = *(const half8*)&At[ra][((kk * 4 + quad) ^ (ra & 7)) * 8];
        int rb = wn + i * 16 + m16;
        bfr[kk][i] = *(const half8*)&Bt[rb][((kk * 4 + quad) ^ (rb & 7)) * 8];
      }
#pragma unroll
    for (int kk = 0; kk < 2; ++kk)
#pragma unroll
      for (int mi = 0; mi < 4; ++mi)
#pragma unroll
        for (int ni = 0; ni < 4; ++ni)
          acc[mi][ni] = __builtin_amdgcn_mfma_f32_16x16x32_f16(
              af[kk][mi], bfr[kk][ni], acc[mi][ni], 0, 0, 0);
  }

  const int ff = flags[0];
#pragma unroll
  for (int ni = 0; ni < 4; ++ni) {
    int cix = col0 + wn + ni * 16 + m16;
    int p = cix >> 9;
    int dd = cix & 511;
    float bias = 0.f;
    if (p > 0) {
      size_t bo = (size_t)layer * 2 * DD + (size_t)(p - 1) * DD + dd;
      bias = ff ? ((const float*)bvec)[bo] : b2f(((const u16*)bvec)[bo]);
    }
#pragma unroll
    for (int mi = 0; mi < 4; ++mi) {
      int r0 = row0 + wm + mi * 16 + quad * 4;
#pragma unroll
      for (int reg = 0; reg < 4; ++reg) {
        float val = acc[mi][ni][reg];
        val = (p == 0) ? val : -(val + bias) * LOG2E;  // exp2-ready planes
        U[(size_t)(r0 + reg) * N3 + cix] = val;
      }
    }
  }
}

// ---- SRU scan: split-recurrence, 4 waves, rcp/exp2 math ----------------
// wave0: c-chain (fma->exp2->add->rcp->fma), publishes (c_prev, cn) ring.
// wave1: h path at one-phase lag. waves 2-3: producers via global_load_lds.
template <int EMIT>
__global__ __launch_bounds__(256, 1)
void scan_kernel(const float* __restrict__ U, float* __restrict__ X,
                 u16* __restrict__ X16,
                 const void* __restrict__ mask_p, const void* __restrict__ vbase,
                 int layer, const int* __restrict__ flags,
                 float* __restrict__ carry, int t0, int nt) {
  __shared__ float bufA[2][2][SB][64];   // [parity][xt|fps][step][lane]
  __shared__ float bufB[3][2][SB][64];   // [k%3][rps|xi][step][lane]
  __shared__ float ring[2][2][SB][64];   // [parity][cprev|cn][step][lane]
  __shared__ int msk[TT];
  const int tid = threadIdx.x;
  const int wave = tid >> 6, lane = tid & 63;
  const int idx0 = blockIdx.x * 64;  // chain base in [0, B*D)
  const int b = idx0 >> 9;           // one b per block
  const int d0 = idx0 & 511;
  const int ff = flags[0], fm = flags[1];

  const int* mi_ = (const int*)mask_p + b * TT;
  const unsigned char* mb_ = (const unsigned char*)mask_p + b * TT;
  for (int i = tid; i < nt; i += 256) msk[i] = fm ? (int)mb_[t0 + i] : mi_[t0 + i];

  float vfs = 0.f, vrs = 0.f, c = 0.f;
  {
    int d = d0 + lane;
    size_t voff = (size_t)layer * 2 * DD;
    if (wave == 0) {
      float vf = ff ? ((const float*)vbase)[voff + d]
                    : b2f(((const u16*)vbase)[voff + d]);
      vfs = -vf * LOG2E;
      c = (t0 == 0) ? 0.f : carry[idx0 + lane];
    } else if (wave == 1) {
      float vr = ff ? ((const float*)vbase)[voff + DD + d]
                    : b2f(((const u16*)vbase)[voff + DD + d]);
      vrs = -vr * LOG2E;
    }
  }

  const int nbuf = nt / SB;

  auto produceA = [&](int k) {  // wave2: xt + fps
    int ph = k & 1, tl = k * SB;
    const float* u0 = U + ((size_t)tl * BB + b) * N3 + d0 + lane;
#pragma unroll
    for (int s = 0; s < SB; ++s)
      async_ld4(u0 + (size_t)s * BB * N3, &bufA[ph][0][s][0]);
#pragma unroll
    for (int s = 0; s < SB; ++s)
      async_ld4(u0 + 512 + (size_t)s * BB * N3, &bufA[ph][1][s][0]);
  };
  auto produceB = [&](int k) {  // wave3: rps + xin
    int ph = k % 3, tl = k * SB;
    const float* u2 = U + ((size_t)tl * BB + b) * N3 + 1024 + d0 + lane;
    const float* xb = X + ((size_t)b * TT + t0 + tl) * DD + d0 + lane;
#pragma unroll
    for (int s = 0; s < SB; ++s)
      async_ld4(u2 + (size_t)s * BB * N3, &bufB[ph][0][s][0]);
#pragma unroll
    for (int s = 0; s < SB; ++s)
      async_ld4(xb + (size_t)s * DD, &bufB[ph][1][s][0]);
  };

  float* Xp = X + (size_t)b * TT * DD + d0 + lane;

  auto hphase = [&](int j) {  // wave1: h for phase j
    int phc = j & 1, phb = j % 3;
#pragma unroll 4
    for (int s = 0; s < SB; ++s) {
      float cprev = ring[phc][0][s][lane];
      float cn = ring[phc][1][s][lane];
      float rps = bufB[phb][0][s][lane];   // pre-scaled -(rp+br)*log2e
      float xin = bufB[phb][1][s][lane];
      int m = msk[j * SB + s];
      float tr = exp2f_(fmaf(vrs, cprev, rps));
      float r = rcpf(1.f + tr);
      float e2 = exp2f_(cn * TWOLOG2E);
      float th = fmaf(-2.f, rcpf(e2 + 1.f), 1.f);
      float h = fmaf(r, th - xin, xin);
      float hout = (m == 0) ? 0.f : h;
      int tg = t0 + j * SB + s;
      Xp[(size_t)tg * DD] = hout;
      if (EMIT)
        X16[((size_t)tg * BB + b) * DD + d0 + lane] = f2h(hout);
    }
  };

  if (wave == 2) produceA(0);
  if (wave == 3) produceB(0);

  for (int k = 0; k < nbuf; ++k) {
    __syncthreads();  // phase-k operands ready; ring[k-1] ready
    if (wave == 2) {
      if (k + 1 < nbuf) produceA(k + 1);
    } else if (wave == 3) {
      if (k + 1 < nbuf) produceB(k + 1);
    } else if (wave == 0) {
      int ph = k & 1;
#pragma unroll 8
      for (int s = 0; s < SB; ++s) {
        float xt = bufA[ph][0][s][lane];
        float fps = bufA[ph][1][s][lane];  // pre-scaled -(fp+bf)*log2e
        float t = exp2f_(fmaf(vfs, c, fps));
        float f = rcpf(1.f + t);
        float cn = fmaf(f, c - xt, xt);
        ring[ph][0][s][lane] = c;
        ring[ph][1][s][lane] = cn;
        c = (msk[k * SB + s] == 0) ? c : cn;
      }
    } else {  // wave 1
      if (k > 0) hphase(k - 1);
    }
  }
  __syncthreads();  // last ring phase visible
  if (wave == 1) hphase(nbuf - 1);
  if (wave == 0) carry[idx0 + lane] = c;
}

__global__ void sentinel_kernel(float* out) { out[threadIdx.x] = 12345.f; }

extern "C" void kernel_launch(void* const* d_in, const int* in_sizes, int n_in,
                              void* d_out, int out_size, void* d_ws, size_t ws_size,
                              hipStream_t stream) {
  const int* ids = (const int*)d_in[0];
  const void* mask = d_in[1];
  const void* emb = d_in[2];
  const void* W = d_in[3];
  const void* v = d_in[4];
  const void* bp = d_in[5];

  char* ws = (char*)d_ws;
  int* flags = (int*)ws;                      // 4 KiB
  float* carry = (float*)(ws + 4096);         // 64 KiB
  const size_t offX16 = 69632;
  const size_t offW16 = offX16 + (size_t)MROWS * DD * 2;   // +16 MiB
  const size_t offU = offW16 + (size_t)LAYERS * WPL * 2;   // +6 MiB
  const size_t perT = (size_t)BB * N3 * 4;    // 196608 B / timestep

  const int cand[4] = {512, 256, 128, 64};  // multiples of 2*SB
  int chunkT = 0;
  for (int i = 0; i < 4; ++i) {
    if (ws_size >= offU + (size_t)cand[i] * perT) { chunkT = cand[i]; break; }
  }
  if (!chunkT) {
    sentinel_kernel<<<1, 256, 0, stream>>>((float*)d_out);
    return;
  }

  u16* X16 = (u16*)(ws + offX16);
  u16* W16 = (u16*)(ws + offW16);
  float* U = (float*)(ws + offU);
  float* X = (float*)d_out;  // (B,T,D) f32

  detect_kernel<<<1, 256, 0, stream>>>((const u16*)emb, (const int*)mask,
                                       (const int*)ids, flags);
  wprep_kernel<<<dim3(16, 48, 4), 256, 0, stream>>>(W, W16, flags);
  embed_kernel<<<MROWS * DD / 256, 256, 0, stream>>>(ids, emb, X, X16, flags);

  int nch = TT / chunkT;
  for (int l = 0; l < LAYERS; ++l) {
    const u16* W16l = W16 + (size_t)l * WPL;
    for (int ch = 0; ch < nch; ++ch) {
      int t0 = ch * chunkT;
      dim3 g(chunkT * BB / 128, N3 / 128);
      gemm_kernel<<<g, 256, 0, stream>>>(X16, W16l, bp, l, flags, U, t0 * BB);
      if (l < LAYERS - 1)
        scan_kernel<1><<<BB * DD / 64, 256, 0, stream>>>(U, X, X16, mask, v, l,
                                                         flags, carry, t0, chunkT);
      else
        scan_kernel<0><<<BB * DD / 64, 256, 0, stream>>>(U, X, X16, mask, v, l,
                                                         flags, carry, t0, chunkT);
    }
  }
}

// Round 12
// 414.609 us; speedup vs baseline: 2.4225x; 1.1528x over previous
//
#include <hip/hip_runtime.h>
#include <hip/hip_bf16.h>

// 4-layer SRU. L=4, B=32, T=512, D=512, V=1000. f32 inputs, f32 output.
// R11: scan widened to 7 waves: wave0 = serial c-chain, waves 1-4 = four
// h-waves (8 steps/phase each, independent), waves 5-6 = producers via
// global_load_lds. rcp/exp2 math and pre-scaled exp planes from R10.

#define LAYERS 4
#define BB 32
#define TT 512
#define DD 512
#define N3 1536
#define MROWS (TT * BB)
#define WPL ((size_t)DD * N3)
#define SB 32                   // steps per phase
#define LOG2E 1.4426950408889634f
#define TWOLOG2E 2.8853900817779268f

typedef unsigned short u16;
typedef _Float16 half8 __attribute__((ext_vector_type(8)));
typedef float f32x4 __attribute__((ext_vector_type(4)));

__device__ __forceinline__ float b2f(u16 u) {
  union { unsigned int i; float f; } x;
  x.i = ((unsigned int)u) << 16;
  return x.f;
}
__device__ __forceinline__ u16 f2h(float f) {
  _Float16 h = (_Float16)f;
  return *(u16*)&h;
}
__device__ __forceinline__ float rcpf(float x) { return __builtin_amdgcn_rcpf(x); }
__device__ __forceinline__ float exp2f_(float x) { return __builtin_amdgcn_exp2f(x); }

__device__ __forceinline__ void async_ld16(const void* g, void* l) {
  __builtin_amdgcn_global_load_lds(
      (const __attribute__((address_space(1))) void*)g,
      (__attribute__((address_space(3))) void*)l, 16, 0, 0);
}
__device__ __forceinline__ void async_ld4(const void* g, void* l) {
  __builtin_amdgcn_global_load_lds(
      (const __attribute__((address_space(1))) void*)g,
      (__attribute__((address_space(3))) void*)l, 4, 0, 0);
}

// ---- dtype detection (flags[0]: floats f32, [1]: mask bytes, [2]: ids int64)
__global__ void detect_kernel(const u16* __restrict__ emb_u,
                              const int* __restrict__ mask_i,
                              const int* __restrict__ ids_i,
                              int* __restrict__ flags) {
  __shared__ int cnt[3];
  __shared__ int zc;
  int tid = threadIdx.x;
  if (tid < 3) cnt[tid] = 0;
  if (tid == 0) zc = 0;
  __syncthreads();
  int bad = 0, zero_even = 0;
  for (int i = tid; i < 8192; i += 256) {
    u16 u = emb_u[i];
    unsigned e = (u >> 7) & 0xFF;
    if (e >= 0x8F) bad++;
    if ((i & 1) == 0 && u == 0) zero_even++;
  }
  if (bad) atomicAdd(&cnt[0], bad);
  if (zero_even) atomicAdd(&zc, zero_even);
  if (tid < 64) {
    unsigned vv = (unsigned)mask_i[tid];
    if (vv > 1u) atomicAdd(&cnt[1], 1);
  }
  if (tid < 256) {
    if (ids_i[2 * tid + 1] == 0) atomicAdd(&cnt[2], 1);
  }
  __syncthreads();
  if (tid == 0) {
    flags[0] = (cnt[0] > 64 || zc > 3000) ? 1 : 0;
    flags[1] = (cnt[1] > 0) ? 1 : 0;
    flags[2] = (cnt[2] >= 192) ? 1 : 0;
  }
}

// ---- W -> f16 transpose: W16[l][n][k] ----------------------------------
__global__ __launch_bounds__(256)
void wprep_kernel(const void* __restrict__ W, u16* __restrict__ W16,
                  const int* __restrict__ flags) {
  __shared__ float tileW[32][33];
  int l = blockIdx.z;
  int k0 = blockIdx.x * 32;
  int n0 = blockIdx.y * 32;
  int tx = threadIdx.x & 31;
  int ty = threadIdx.x >> 5;
  int ff = flags[0];
  const float* Wf = (const float*)W + (size_t)l * WPL;
  const u16* Wb = (const u16*)W + (size_t)l * WPL;
  for (int kk = ty; kk < 32; kk += 8) {
    size_t off = (size_t)(k0 + kk) * N3 + n0 + tx;
    tileW[kk][tx] = ff ? Wf[off] : b2f(Wb[off]);
  }
  __syncthreads();
  u16* outP = W16 + (size_t)l * WPL;
  for (int nn = ty; nn < 32; nn += 8) {
    float x = tileW[tx][nn];
    outP[(size_t)(n0 + nn) * DD + k0 + tx] = f2h(x);
  }
}

// ---- embedding: X f32 (B,T,D) = d_out; X16 f16 (T,B,D) -----------------
__global__ void embed_kernel(const int* __restrict__ ids,
                             const void* __restrict__ emb,
                             float* __restrict__ X,
                             u16* __restrict__ X16,
                             const int* __restrict__ flags) {
  int i = blockIdx.x * 256 + threadIdx.x;
  int d = i & (DD - 1);
  int tb = i >> 9;
  int b = tb & (BB - 1);
  int t = tb >> 5;
  int ii = b * TT + t;
  int id = flags[2] ? ids[2 * ii] : ids[ii];
  float val = flags[0] ? ((const float*)emb)[id * DD + d]
                       : b2f(((const u16*)emb)[id * DD + d]);
  X[((size_t)b * TT + t) * DD + d] = val;
  X16[i] = f2h(val);
}

// ---- MFMA fp16 GEMM (R8): K=512, BK=64, XOR-swizzled async staging -----
// Epilogue: plane0 = acc (xt); planes 1,2 = -(acc+bias)*log2e (exp-ready).
__global__ __launch_bounds__(256)
void gemm_kernel(const u16* __restrict__ X16, const u16* __restrict__ W16l,
                 const void* __restrict__ bvec, int layer,
                 const int* __restrict__ flags,
                 float* __restrict__ U, int row_base) {
  __shared__ u16 At[128][64];
  __shared__ u16 Bt[128][64];
  const int tid = threadIdx.x;
  const int row0 = blockIdx.x * 128;
  const int col0 = blockIdx.y * 128;
  const int lane = tid & 63, wave = tid >> 6;
  const int wm = (wave >> 1) * 64, wn = (wave & 1) * 64;
  const int m16 = lane & 15, quad = lane >> 4;
  const int isA = (wave < 2);
  const int rbase = (wave & 1) * 64;
  const int srow = lane >> 3;
  const int sseg = (lane & 7) ^ (srow & 7);

  f32x4 acc[4][4];
#pragma unroll
  for (int mi = 0; mi < 4; ++mi)
#pragma unroll
    for (int ni = 0; ni < 4; ++ni)
#pragma unroll
      for (int r = 0; r < 4; ++r) acc[mi][ni][r] = 0.f;

  const u16* srcBase = isA ? X16 : W16l;
  const int gbase = isA ? (row_base + row0 + rbase) : (col0 + rbase);

  for (int kv = 0; kv < 512; kv += 64) {
    __syncthreads();
    {
      const u16* src = srcBase + (size_t)(gbase + srow) * DD + kv + sseg * 8;
      u16(*dst)[64] = isA ? At : Bt;
#pragma unroll
      for (int i = 0; i < 8; ++i)
        async_ld16(src + (size_t)i * 8 * DD, &dst[rbase + i * 8][0]);
    }
    __syncthreads();

    half8 af[2][4], bfr[2][4];
#pragma unroll
    for (int kk = 0; kk < 2; ++kk)
#pragma unroll
      for (int i = 0; i < 4; ++i) {
        int ra = wm + i * 16 + m16;
        af[kk][i] = *(const half8*)&At[ra][((kk * 4 + quad) ^ (ra & 7)) * 8];
        int rb = wn + i * 16 + m16;
        bfr[kk][i] = *(const half8*)&Bt[rb][((kk * 4 + quad) ^ (rb & 7)) * 8];
      }
#pragma unroll
    for (int kk = 0; kk < 2; ++kk)
#pragma unroll
      for (int mi = 0; mi < 4; ++mi)
#pragma unroll
        for (int ni = 0; ni < 4; ++ni)
          acc[mi][ni] = __builtin_amdgcn_mfma_f32_16x16x32_f16(
              af[kk][mi], bfr[kk][ni], acc[mi][ni], 0, 0, 0);
  }

  const int ff = flags[0];
#pragma unroll
  for (int ni = 0; ni < 4; ++ni) {
    int cix = col0 + wn + ni * 16 + m16;
    int p = cix >> 9;
    int dd = cix & 511;
    float bias = 0.f;
    if (p > 0) {
      size_t bo = (size_t)layer * 2 * DD + (size_t)(p - 1) * DD + dd;
      bias = ff ? ((const float*)bvec)[bo] : b2f(((const u16*)bvec)[bo]);
    }
#pragma unroll
    for (int mi = 0; mi < 4; ++mi) {
      int r0 = row0 + wm + mi * 16 + quad * 4;
#pragma unroll
      for (int reg = 0; reg < 4; ++reg) {
        float val = acc[mi][ni][reg];
        val = (p == 0) ? val : -(val + bias) * LOG2E;  // exp2-ready planes
        U[(size_t)(r0 + reg) * N3 + cix] = val;
      }
    }
  }
}

// ---- SRU scan: split-recurrence, 7 waves -------------------------------
// wave0: c-chain, publishes (c_prev, cn) ring. waves1-4: h path, 8 steps
// per phase each, one-phase lag. wave5: xt/fps producer. wave6: rps/xi.
template <int EMIT>
__global__ __launch_bounds__(448, 1)
void scan_kernel(const float* __restrict__ U, float* __restrict__ X,
                 u16* __restrict__ X16,
                 const void* __restrict__ mask_p, const void* __restrict__ vbase,
                 int layer, const int* __restrict__ flags,
                 float* __restrict__ carry, int t0, int nt) {
  __shared__ float bufA[2][2][SB][64];   // [parity][xt|fps][step][lane]
  __shared__ float bufB[3][2][SB][64];   // [k%3][rps|xi][step][lane]
  __shared__ float ring[2][2][SB][64];   // [parity][cprev|cn][step][lane]
  __shared__ int msk[TT];
  const int tid = threadIdx.x;
  const int wave = tid >> 6, lane = tid & 63;
  const int idx0 = blockIdx.x * 64;  // chain base in [0, B*D)
  const int b = idx0 >> 9;           // one b per block
  const int d0 = idx0 & 511;
  const int ff = flags[0], fm = flags[1];

  const int* mi_ = (const int*)mask_p + b * TT;
  const unsigned char* mb_ = (const unsigned char*)mask_p + b * TT;
  for (int i = tid; i < nt; i += 448) msk[i] = fm ? (int)mb_[t0 + i] : mi_[t0 + i];

  float vfs = 0.f, vrs = 0.f, c = 0.f;
  {
    int d = d0 + lane;
    size_t voff = (size_t)layer * 2 * DD;
    if (wave == 0) {
      float vf = ff ? ((const float*)vbase)[voff + d]
                    : b2f(((const u16*)vbase)[voff + d]);
      vfs = -vf * LOG2E;
      c = (t0 == 0) ? 0.f : carry[idx0 + lane];
    } else if (wave >= 1 && wave <= 4) {
      float vr = ff ? ((const float*)vbase)[voff + DD + d]
                    : b2f(((const u16*)vbase)[voff + DD + d]);
      vrs = -vr * LOG2E;
    }
  }

  const int nbuf = nt / SB;

  auto produceA = [&](int k) {  // wave5: xt + fps
    int ph = k & 1, tl = k * SB;
    const float* u0 = U + ((size_t)tl * BB + b) * N3 + d0 + lane;
#pragma unroll
    for (int s = 0; s < SB; ++s)
      async_ld4(u0 + (size_t)s * BB * N3, &bufA[ph][0][s][0]);
#pragma unroll
    for (int s = 0; s < SB; ++s)
      async_ld4(u0 + 512 + (size_t)s * BB * N3, &bufA[ph][1][s][0]);
  };
  auto produceB = [&](int k) {  // wave6: rps + xin
    int ph = k % 3, tl = k * SB;
    const float* u2 = U + ((size_t)tl * BB + b) * N3 + 1024 + d0 + lane;
    const float* xb = X + ((size_t)b * TT + t0 + tl) * DD + d0 + lane;
#pragma unroll
    for (int s = 0; s < SB; ++s)
      async_ld4(u2 + (size_t)s * BB * N3, &bufB[ph][0][s][0]);
#pragma unroll
    for (int s = 0; s < SB; ++s)
      async_ld4(xb + (size_t)s * DD, &bufB[ph][1][s][0]);
  };

  float* Xp = X + (size_t)b * TT * DD + d0 + lane;

  // h-wave hw (0..3) handles steps [hw*8, hw*8+8) of phase j
  auto hphase = [&](int j, int hw) {
    int phc = j & 1, phb = j % 3;
    int sbase = hw * (SB / 4);
#pragma unroll
    for (int si = 0; si < SB / 4; ++si) {
      int s = sbase + si;
      float cprev = ring[phc][0][s][lane];
      float cn = ring[phc][1][s][lane];
      float rps = bufB[phb][0][s][lane];   // pre-scaled -(rp+br)*log2e
      float xin = bufB[phb][1][s][lane];
      int m = msk[j * SB + s];
      float tr = exp2f_(fmaf(vrs, cprev, rps));
      float r = rcpf(1.f + tr);
      float e2 = exp2f_(cn * TWOLOG2E);
      float th = fmaf(-2.f, rcpf(e2 + 1.f), 1.f);
      float h = fmaf(r, th - xin, xin);
      float hout = (m == 0) ? 0.f : h;
      int tg = t0 + j * SB + s;
      Xp[(size_t)tg * DD] = hout;
      if (EMIT)
        X16[((size_t)tg * BB + b) * DD + d0 + lane] = f2h(hout);
    }
  };

  if (wave == 5) produceA(0);
  if (wave == 6) produceB(0);

  for (int k = 0; k < nbuf; ++k) {
    __syncthreads();  // phase-k operands ready; ring[k-1] ready
    if (wave == 5) {
      if (k + 1 < nbuf) produceA(k + 1);
    } else if (wave == 6) {
      if (k + 1 < nbuf) produceB(k + 1);
    } else if (wave == 0) {
      int ph = k & 1;
#pragma unroll 8
      for (int s = 0; s < SB; ++s) {
        float xt = bufA[ph][0][s][lane];
        float fps = bufA[ph][1][s][lane];  // pre-scaled -(fp+bf)*log2e
        float t = exp2f_(fmaf(vfs, c, fps));
        float f = rcpf(1.f + t);
        float cn = fmaf(f, c - xt, xt);
        ring[ph][0][s][lane] = c;
        ring[ph][1][s][lane] = cn;
        c = (msk[k * SB + s] == 0) ? c : cn;
      }
    } else {  // waves 1-4: h path
      if (k > 0) hphase(k - 1, wave - 1);
    }
  }
  __syncthreads();  // last ring phase visible
  if (wave >= 1 && wave <= 4) hphase(nbuf - 1, wave - 1);
  if (wave == 0) carry[idx0 + lane] = c;
}

__global__ void sentinel_kernel(float* out) { out[threadIdx.x] = 12345.f; }

extern "C" void kernel_launch(void* const* d_in, const int* in_sizes, int n_in,
                              void* d_out, int out_size, void* d_ws, size_t ws_size,
                              hipStream_t stream) {
  const int* ids = (const int*)d_in[0];
  const void* mask = d_in[1];
  const void* emb = d_in[2];
  const void* W = d_in[3];
  const void* v = d_in[4];
  const void* bp = d_in[5];

  char* ws = (char*)d_ws;
  int* flags = (int*)ws;                      // 4 KiB
  float* carry = (float*)(ws + 4096);         // 64 KiB
  const size_t offX16 = 69632;
  const size_t offW16 = offX16 + (size_t)MROWS * DD * 2;   // +16 MiB
  const size_t offU = offW16 + (size_t)LAYERS * WPL * 2;   // +6 MiB
  const size_t perT = (size_t)BB * N3 * 4;    // 196608 B / timestep

  const int cand[4] = {512, 256, 128, 64};  // multiples of 2*SB
  int chunkT = 0;
  for (int i = 0; i < 4; ++i) {
    if (ws_size >= offU + (size_t)cand[i] * perT) { chunkT = cand[i]; break; }
  }
  if (!chunkT) {
    sentinel_kernel<<<1, 256, 0, stream>>>((float*)d_out);
    return;
  }

  u16* X16 = (u16*)(ws + offX16);
  u16* W16 = (u16*)(ws + offW16);
  float* U = (float*)(ws + offU);
  float* X = (float*)d_out;  // (B,T,D) f32

  detect_kernel<<<1, 256, 0, stream>>>((const u16*)emb, (const int*)mask,
                                       (const int*)ids, flags);
  wprep_kernel<<<dim3(16, 48, 4), 256, 0, stream>>>(W, W16, flags);
  embed_kernel<<<MROWS * DD / 256, 256, 0, stream>>>(ids, emb, X, X16, flags);

  int nch = TT / chunkT;
  for (int l = 0; l < LAYERS; ++l) {
    const u16* W16l = W16 + (size_t)l * WPL;
    for (int ch = 0; ch < nch; ++ch) {
      int t0 = ch * chunkT;
      dim3 g(chunkT * BB / 128, N3 / 128);
      gemm_kernel<<<g, 256, 0, stream>>>(X16, W16l, bp, l, flags, U, t0 * BB);
      if (l < LAYERS - 1)
        scan_kernel<1><<<BB * DD / 64, 448, 0, stream>>>(U, X, X16, mask, v, l,
                                                         flags, carry, t0, chunkT);
      else
        scan_kernel<0><<<BB * DD / 64, 448, 0, stream>>>(U, X, X16, mask, v, l,
                                                         flags, carry, t0, chunkT);
    }
  }
}

// Round 13
// 346.476 us; speedup vs baseline: 2.8988x; 1.1966x over previous
//
#include <hip/hip_runtime.h>
#include <hip/hip_bf16.h>

// 4-layer SRU. L=4, B=32, T=512, D=512, V=1000. f32 inputs, f32 output.
// R12: U stored as three planar f16 planes (xt, fps, rps — exp-planes
// pre-scaled by -log2e); xi flows through X16 (f16); only the final layer
// writes f32 to d_out. Scan producers: one async_ld4 covers 2 timesteps
// (per-lane global addresses, contiguous LDS dest). 7-wave scan from R11.

#define LAYERS 4
#define BB 32
#define TT 512
#define DD 512
#define N3 1536
#define MROWS (TT * BB)
#define WPL ((size_t)DD * N3)
#define SB 32                   // steps per phase
#define LOG2E 1.4426950408889634f
#define TWOLOG2E 2.8853900817779268f

typedef unsigned short u16;
typedef unsigned int u32;
typedef _Float16 half8 __attribute__((ext_vector_type(8)));
typedef float f32x4 __attribute__((ext_vector_type(4)));

__device__ __forceinline__ float b2f(u16 u) {
  union { unsigned int i; float f; } x;
  x.i = ((unsigned int)u) << 16;
  return x.f;
}
__device__ __forceinline__ u16 f2h(float f) {
  _Float16 h = (_Float16)f;
  return *(u16*)&h;
}
__device__ __forceinline__ float h2f(u16 u) {
  _Float16 h;
  *(u16*)&h = u;
  return (float)h;
}
__device__ __forceinline__ float rcpf(float x) { return __builtin_amdgcn_rcpf(x); }
__device__ __forceinline__ float exp2f_(float x) { return __builtin_amdgcn_exp2f(x); }

__device__ __forceinline__ void async_ld16(const void* g, void* l) {
  __builtin_amdgcn_global_load_lds(
      (const __attribute__((address_space(1))) void*)g,
      (__attribute__((address_space(3))) void*)l, 16, 0, 0);
}
__device__ __forceinline__ void async_ld4(const void* g, void* l) {
  __builtin_amdgcn_global_load_lds(
      (const __attribute__((address_space(1))) void*)g,
      (__attribute__((address_space(3))) void*)l, 4, 0, 0);
}

// ---- dtype detection (flags[0]: floats f32, [1]: mask bytes, [2]: ids int64)
__global__ void detect_kernel(const u16* __restrict__ emb_u,
                              const int* __restrict__ mask_i,
                              const int* __restrict__ ids_i,
                              int* __restrict__ flags) {
  __shared__ int cnt[3];
  __shared__ int zc;
  int tid = threadIdx.x;
  if (tid < 3) cnt[tid] = 0;
  if (tid == 0) zc = 0;
  __syncthreads();
  int bad = 0, zero_even = 0;
  for (int i = tid; i < 8192; i += 256) {
    u16 u = emb_u[i];
    unsigned e = (u >> 7) & 0xFF;
    if (e >= 0x8F) bad++;
    if ((i & 1) == 0 && u == 0) zero_even++;
  }
  if (bad) atomicAdd(&cnt[0], bad);
  if (zero_even) atomicAdd(&zc, zero_even);
  if (tid < 64) {
    unsigned vv = (unsigned)mask_i[tid];
    if (vv > 1u) atomicAdd(&cnt[1], 1);
  }
  if (tid < 256) {
    if (ids_i[2 * tid + 1] == 0) atomicAdd(&cnt[2], 1);
  }
  __syncthreads();
  if (tid == 0) {
    flags[0] = (cnt[0] > 64 || zc > 3000) ? 1 : 0;
    flags[1] = (cnt[1] > 0) ? 1 : 0;
    flags[2] = (cnt[2] >= 192) ? 1 : 0;
  }
}

// ---- W -> f16 transpose: W16[l][n][k] ----------------------------------
__global__ __launch_bounds__(256)
void wprep_kernel(const void* __restrict__ W, u16* __restrict__ W16,
                  const int* __restrict__ flags) {
  __shared__ float tileW[32][33];
  int l = blockIdx.z;
  int k0 = blockIdx.x * 32;
  int n0 = blockIdx.y * 32;
  int tx = threadIdx.x & 31;
  int ty = threadIdx.x >> 5;
  int ff = flags[0];
  const float* Wf = (const float*)W + (size_t)l * WPL;
  const u16* Wb = (const u16*)W + (size_t)l * WPL;
  for (int kk = ty; kk < 32; kk += 8) {
    size_t off = (size_t)(k0 + kk) * N3 + n0 + tx;
    tileW[kk][tx] = ff ? Wf[off] : b2f(Wb[off]);
  }
  __syncthreads();
  u16* outP = W16 + (size_t)l * WPL;
  for (int nn = ty; nn < 32; nn += 8) {
    float x = tileW[tx][nn];
    outP[(size_t)(n0 + nn) * DD + k0 + tx] = f2h(x);
  }
}

// ---- embedding: X16 f16 (T,B,D) only -----------------------------------
__global__ void embed_kernel(const int* __restrict__ ids,
                             const void* __restrict__ emb,
                             u16* __restrict__ X16,
                             const int* __restrict__ flags) {
  int i = blockIdx.x * 256 + threadIdx.x;  // (t,b,d) linear
  int d = i & (DD - 1);
  int tb = i >> 9;
  int b = tb & (BB - 1);
  int t = tb >> 5;
  int ii = b * TT + t;
  int id = flags[2] ? ids[2 * ii] : ids[ii];
  float val = flags[0] ? ((const float*)emb)[id * DD + d]
                       : b2f(((const u16*)emb)[id * DD + d]);
  X16[i] = f2h(val);
}

// ---- MFMA fp16 GEMM: three f16 output planes ---------------------------
// plane0 = xt; planes 1,2 = -(acc+bias)*log2e (exp2-ready), all f16.
// U16 plane p base = U16 + p*chunkM*512; column cix -> (p=cix>>9, dd=cix&511).
__global__ __launch_bounds__(256)
void gemm_kernel(const u16* __restrict__ X16, const u16* __restrict__ W16l,
                 const void* __restrict__ bvec, int layer,
                 const int* __restrict__ flags,
                 u16* __restrict__ U16, int row_base, int chunkM) {
  __shared__ u16 At[128][64];
  __shared__ u16 Bt[128][64];
  const int tid = threadIdx.x;
  const int row0 = blockIdx.x * 128;
  const int col0 = blockIdx.y * 128;
  const int lane = tid & 63, wave = tid >> 6;
  const int wm = (wave >> 1) * 64, wn = (wave & 1) * 64;
  const int m16 = lane & 15, quad = lane >> 4;
  const int isA = (wave < 2);
  const int rbase = (wave & 1) * 64;
  const int srow = lane >> 3;
  const int sseg = (lane & 7) ^ (srow & 7);

  f32x4 acc[4][4];
#pragma unroll
  for (int mi = 0; mi < 4; ++mi)
#pragma unroll
    for (int ni = 0; ni < 4; ++ni)
#pragma unroll
      for (int r = 0; r < 4; ++r) acc[mi][ni][r] = 0.f;

  const u16* srcBase = isA ? X16 : W16l;
  const int gbase = isA ? (row_base + row0 + rbase) : (col0 + rbase);

  for (int kv = 0; kv < 512; kv += 64) {
    __syncthreads();
    {
      const u16* src = srcBase + (size_t)(gbase + srow) * DD + kv + sseg * 8;
      u16(*dst)[64] = isA ? At : Bt;
#pragma unroll
      for (int i = 0; i < 8; ++i)
        async_ld16(src + (size_t)i * 8 * DD, &dst[rbase + i * 8][0]);
    }
    __syncthreads();

    half8 af[2][4], bfr[2][4];
#pragma unroll
    for (int kk = 0; kk < 2; ++kk)
#pragma unroll
      for (int i = 0; i < 4; ++i) {
        int ra = wm + i * 16 + m16;
        af[kk][i] = *(const half8*)&At[ra][((kk * 4 + quad) ^ (ra & 7)) * 8];
        int rb = wn + i * 16 + m16;
        bfr[kk][i] = *(const half8*)&Bt[rb][((kk * 4 + quad) ^ (rb & 7)) * 8];
      }
#pragma unroll
    for (int kk = 0; kk < 2; ++kk)
#pragma unroll
      for (int mi = 0; mi < 4; ++mi)
#pragma unroll
        for (int ni = 0; ni < 4; ++ni)
          acc[mi][ni] = __builtin_amdgcn_mfma_f32_16x16x32_f16(
              af[kk][mi], bfr[kk][ni], acc[mi][ni], 0, 0, 0);
  }

  const int ff = flags[0];
#pragma unroll
  for (int ni = 0; ni < 4; ++ni) {
    int cix = col0 + wn + ni * 16 + m16;
    int p = cix >> 9;
    int dd = cix & 511;
    float bias = 0.f;
    if (p > 0) {
      size_t bo = (size_t)layer * 2 * DD + (size_t)(p - 1) * DD + dd;
      bias = ff ? ((const float*)bvec)[bo] : b2f(((const u16*)bvec)[bo]);
    }
    u16* up = U16 + (size_t)p * chunkM * 512;
#pragma unroll
    for (int mi = 0; mi < 4; ++mi) {
      int r0 = row0 + wm + mi * 16 + quad * 4;
#pragma unroll
      for (int reg = 0; reg < 4; ++reg) {
        float val = acc[mi][ni][reg];
        val = (p == 0) ? val : -(val + bias) * LOG2E;  // exp2-ready planes
        up[(size_t)(r0 + reg) * 512 + dd] = f2h(val);
      }
    }
  }
}

// ---- SRU scan: split-recurrence, 7 waves, f16 operand streams ----------
// wave0: c-chain. waves1-4: h path (8 steps/phase each, one-phase lag).
// wave5: xt/fps producer. wave6: rps/xi producer. Each async_ld4 covers
// TWO timesteps of a u16 stream (per-lane global addr, contiguous LDS).
// EMIT=1 (layers 0-2): write X16 f16 only. EMIT=0 (final): write X f32.
template <int EMIT>
__global__ __launch_bounds__(448, 1)
void scan_kernel(const u16* __restrict__ U16, float* __restrict__ X,
                 u16* __restrict__ X16,
                 const void* __restrict__ mask_p, const void* __restrict__ vbase,
                 int layer, const int* __restrict__ flags,
                 float* __restrict__ carry, int t0, int nt, int chunkM) {
  __shared__ u16 bufA[2][2][SB][64];   // [parity][xt|fps][step][lane]
  __shared__ u16 bufB[3][2][SB][64];   // [k%3][rps|xi][step][lane]
  __shared__ float ring[2][2][SB][64]; // [parity][cprev|cn][step][lane]
  __shared__ int msk[TT];
  const int tid = threadIdx.x;
  const int wave = tid >> 6, lane = tid & 63;
  const int idx0 = blockIdx.x * 64;  // chain base in [0, B*D)
  const int b = idx0 >> 9;           // one b per block
  const int d0 = idx0 & 511;
  const int ff = flags[0], fm = flags[1];

  const int* mi_ = (const int*)mask_p + b * TT;
  const unsigned char* mb_ = (const unsigned char*)mask_p + b * TT;
  for (int i = tid; i < nt; i += 448) msk[i] = fm ? (int)mb_[t0 + i] : mi_[t0 + i];

  float vfs = 0.f, vrs = 0.f, c = 0.f;
  {
    int d = d0 + lane;
    size_t voff = (size_t)layer * 2 * DD;
    if (wave == 0) {
      float vf = ff ? ((const float*)vbase)[voff + d]
                    : b2f(((const u16*)vbase)[voff + d]);
      vfs = -vf * LOG2E;
      c = (t0 == 0) ? 0.f : carry[idx0 + lane];
    } else if (wave >= 1 && wave <= 4) {
      float vr = ff ? ((const float*)vbase)[voff + DD + d]
                    : b2f(((const u16*)vbase)[voff + DD + d]);
      vrs = -vr * LOG2E;
    }
  }

  const int nbuf = nt / SB;

  // u16-stream pair load: lanes 0-31 -> step s, lanes 32-63 -> step s+1
  auto ld_pair = [&](const u16* rowS, const u16* rowS1, void* ldst) {
    const u32* a0 = (const u32*)rowS;
    const u32* a1 = (const u32*)rowS1;
    const u32* ga = (lane < 32) ? (a0 + lane) : (a1 + (lane - 32));
    async_ld4(ga, ldst);
  };

  auto produceA = [&](int k) {  // wave5: xt (plane0) + fps (plane1)
    int ph = k & 1, tl = k * SB;
    const u16* p0 = U16 + ((size_t)tl * BB + b) * 512 + d0;
    const u16* p1 = p0 + (size_t)chunkM * 512;
#pragma unroll
    for (int s = 0; s < SB; s += 2)
      ld_pair(p0 + (size_t)s * BB * 512, p0 + (size_t)(s + 1) * BB * 512,
              &bufA[ph][0][s][0]);
#pragma unroll
    for (int s = 0; s < SB; s += 2)
      ld_pair(p1 + (size_t)s * BB * 512, p1 + (size_t)(s + 1) * BB * 512,
              &bufA[ph][1][s][0]);
  };
  auto produceB = [&](int k) {  // wave6: rps (plane2) + xi (X16)
    int ph = k % 3, tl = k * SB;
    const u16* p2 = U16 + 2 * (size_t)chunkM * 512 + ((size_t)tl * BB + b) * 512 + d0;
    const u16* xb = X16 + ((size_t)(t0 + tl) * BB + b) * DD + d0;
#pragma unroll
    for (int s = 0; s < SB; s += 2)
      ld_pair(p2 + (size_t)s * BB * 512, p2 + (size_t)(s + 1) * BB * 512,
              &bufB[ph][0][s][0]);
#pragma unroll
    for (int s = 0; s < SB; s += 2)
      ld_pair(xb + (size_t)s * BB * DD, xb + (size_t)(s + 1) * BB * DD,
              &bufB[ph][1][s][0]);
  };

  float* Xp = X + (size_t)b * TT * DD + d0 + lane;

  // h-wave hw (0..3) handles steps [hw*8, hw*8+8) of phase j
  auto hphase = [&](int j, int hw) {
    int phc = j & 1, phb = j % 3;
    int sbase = hw * (SB / 4);
#pragma unroll
    for (int si = 0; si < SB / 4; ++si) {
      int s = sbase + si;
      float cprev = ring[phc][0][s][lane];
      float cn = ring[phc][1][s][lane];
      float rps = h2f(bufB[phb][0][s][lane]);
      float xin = h2f(bufB[phb][1][s][lane]);
      int m = msk[j * SB + s];
      float tr = exp2f_(fmaf(vrs, cprev, rps));
      float r = rcpf(1.f + tr);
      float e2 = exp2f_(cn * TWOLOG2E);
      float th = fmaf(-2.f, rcpf(e2 + 1.f), 1.f);
      float h = fmaf(r, th - xin, xin);
      float hout = (m == 0) ? 0.f : h;
      int tg = t0 + j * SB + s;
      if (EMIT)
        X16[((size_t)tg * BB + b) * DD + d0 + lane] = f2h(hout);
      else
        Xp[(size_t)tg * DD] = hout;
    }
  };

  if (wave == 5) produceA(0);
  if (wave == 6) produceB(0);

  for (int k = 0; k < nbuf; ++k) {
    __syncthreads();  // phase-k operands ready; ring[k-1] ready
    if (wave == 5) {
      if (k + 1 < nbuf) produceA(k + 1);
    } else if (wave == 6) {
      if (k + 1 < nbuf) produceB(k + 1);
    } else if (wave == 0) {
      int ph = k & 1;
#pragma unroll 8
      for (int s = 0; s < SB; ++s) {
        float xt = h2f(bufA[ph][0][s][lane]);
        float fps = h2f(bufA[ph][1][s][lane]);  // pre-scaled -(fp+bf)*log2e
        float t = exp2f_(fmaf(vfs, c, fps));
        float f = rcpf(1.f + t);
        float cn = fmaf(f, c - xt, xt);
        ring[ph][0][s][lane] = c;
        ring[ph][1][s][lane] = cn;
        c = (msk[k * SB + s] == 0) ? c : cn;
      }
    } else {  // waves 1-4: h path
      if (k > 0) hphase(k - 1, wave - 1);
    }
  }
  __syncthreads();  // last ring phase visible
  if (wave >= 1 && wave <= 4) hphase(nbuf - 1, wave - 1);
  if (wave == 0) carry[idx0 + lane] = c;
}

__global__ void sentinel_kernel(float* out) { out[threadIdx.x] = 12345.f; }

extern "C" void kernel_launch(void* const* d_in, const int* in_sizes, int n_in,
                              void* d_out, int out_size, void* d_ws, size_t ws_size,
                              hipStream_t stream) {
  const int* ids = (const int*)d_in[0];
  const void* mask = d_in[1];
  const void* emb = d_in[2];
  const void* W = d_in[3];
  const void* v = d_in[4];
  const void* bp = d_in[5];

  char* ws = (char*)d_ws;
  int* flags = (int*)ws;                      // 4 KiB
  float* carry = (float*)(ws + 4096);         // 64 KiB
  const size_t offX16 = 69632;
  const size_t offW16 = offX16 + (size_t)MROWS * DD * 2;   // +16 MiB
  const size_t offU = offW16 + (size_t)LAYERS * WPL * 2;   // +6 MiB
  const size_t perT = (size_t)BB * N3 * 2;    // 98304 B / timestep (3 f16 planes)

  const int cand[4] = {512, 256, 128, 64};  // multiples of 2*SB
  int chunkT = 0;
  for (int i = 0; i < 4; ++i) {
    if (ws_size >= offU + (size_t)cand[i] * perT) { chunkT = cand[i]; break; }
  }
  if (!chunkT) {
    sentinel_kernel<<<1, 256, 0, stream>>>((float*)d_out);
    return;
  }
  const int chunkM = chunkT * BB;

  u16* X16 = (u16*)(ws + offX16);
  u16* W16 = (u16*)(ws + offW16);
  u16* U16 = (u16*)(ws + offU);
  float* X = (float*)d_out;  // (B,T,D) f32 — final output only

  detect_kernel<<<1, 256, 0, stream>>>((const u16*)emb, (const int*)mask,
                                       (const int*)ids, flags);
  wprep_kernel<<<dim3(16, 48, 4), 256, 0, stream>>>(W, W16, flags);
  embed_kernel<<<MROWS * DD / 256, 256, 0, stream>>>(ids, emb, X16, flags);

  int nch = TT / chunkT;
  for (int l = 0; l < LAYERS; ++l) {
    const u16* W16l = W16 + (size_t)l * WPL;
    for (int ch = 0; ch < nch; ++ch) {
      int t0 = ch * chunkT;
      dim3 g(chunkT * BB / 128, N3 / 128);
      gemm_kernel<<<g, 256, 0, stream>>>(X16, W16l, bp, l, flags, U16,
                                         t0 * BB, chunkM);
      if (l < LAYERS - 1)
        scan_kernel<1><<<BB * DD / 64, 448, 0, stream>>>(U16, X, X16, mask, v, l,
                                                         flags, carry, t0, chunkT,
                                                         chunkM);
      else
        scan_kernel<0><<<BB * DD / 64, 448, 0, stream>>>(U16, X, X16, mask, v, l,
                                                         flags, carry, t0, chunkT,
                                                         chunkM);
    }
  }
}